// Round 11
// baseline (481.007 us; speedup 1.0000x reference)
//
#include <hip/hip_runtime.h>
#include <hip/hip_bf16.h>
#include <math.h>

#define B_    64
#define T_    256
#define EMB_  300
#define HW_   128
#define G4_   512     // 4*HW
#define P1_   46
#define NPOS  (B_*T_) // 16384

typedef short  short8 __attribute__((ext_vector_type(8)));
typedef float  f32x4  __attribute__((ext_vector_type(4)));

__device__ __forceinline__ float sigmoidf_(float x) {
  return 1.0f / (1.0f + __expf(-x));
}
__device__ __forceinline__ float ftanh_(float x) {
  float e = __expf(2.0f * x);
  return 1.0f - 2.0f / (e + 1.0f);
}
__device__ __forceinline__ unsigned short f2bf(float x) {   // RNE fp32->bf16
  unsigned u = __float_as_uint(x);
  u += 0x7fffu + ((u >> 16) & 1u);
  return (unsigned short)(u >> 16);
}
__device__ __forceinline__ float bf2f(unsigned short u) {
  return __uint_as_float(((unsigned)u) << 16);
}
template<int CTRL>
__device__ __forceinline__ float qb(float v) {   // quad_perm broadcast (DPP, VALU)
  return __int_as_float(__builtin_amdgcn_mov_dpp(__float_as_int(v), CTRL, 0xf, 0xf, true));
}
__device__ __forceinline__ void gload_lds16(const unsigned short* g, unsigned short* l) {
  __builtin_amdgcn_global_load_lds(
      (const __attribute__((address_space(1))) unsigned int*)g,
      (__attribute__((address_space(3))) unsigned int*)l, 16, 0, 0);
}

// ---------------------------------------------------------------------------
// Kernel 0: pre-cast. embB[m][0..320) = bf16(emb[words[m]][k]) (zero-pad
// k>=300); wB[n][0..320) = bf16 of [WiF;WiB] rows. 8 cols per thread.
// ---------------------------------------------------------------------------
__global__ __launch_bounds__(256) void cast_k(
    const int* __restrict__ words, const float* __restrict__ emb,
    const float* __restrict__ WiF, const float* __restrict__ WiB,
    unsigned short* __restrict__ embB, unsigned short* __restrict__ wB) {
  const int u = blockIdx.x * 256 + threadIdx.x;   // < 696320
  const float* src;
  unsigned short* dst;
  int k;
  if (u < 655360) {
    const int m = u / 40, kc = u - m * 40;
    k = kc * 8;
    src = emb + (long)words[m] * EMB_ + k;
    dst = embB + (long)m * 320 + k;
  } else {
    const int u2 = u - 655360;                    // < 40960
    const int n = u2 / 40, kc = u2 - n * 40;
    k = kc * 8;
    src = ((n < G4_) ? WiF + (long)n * EMB_ : WiB + (long)(n - G4_) * EMB_) + k;
    dst = wB + (long)n * 320 + k;
  }
  union { unsigned short us[8]; short8 v; } o;
  if (k + 8 <= EMB_) {
    const float4 a = *(const float4*)src;
    const float4 b = *(const float4*)(src + 4);
    o.us[0]=f2bf(a.x); o.us[1]=f2bf(a.y); o.us[2]=f2bf(a.z); o.us[3]=f2bf(a.w);
    o.us[4]=f2bf(b.x); o.us[5]=f2bf(b.y); o.us[6]=f2bf(b.z); o.us[7]=f2bf(b.w);
  } else if (k < EMB_) {                          // k == 296
    const float4 a = *(const float4*)src;
    o.us[0]=f2bf(a.x); o.us[1]=f2bf(a.y); o.us[2]=f2bf(a.z); o.us[3]=f2bf(a.w);
    o.us[4]=0; o.us[5]=0; o.us[6]=0; o.us[7]=0;
  } else {
    #pragma unroll
    for (int e = 0; e < 8; ++e) o.us[e] = 0;
  }
  *(short8*)dst = o.v;
}

// ---------------------------------------------------------------------------
// Kernel 1: blocks [0,128) = pos LSTM; blocks [128,2176) = xg GEMM from the
// pre-cast bf16 tensors via global_load_lds (pre-swizzled source, linear LDS).
// xg (bf16): gate-block g's columns rotated by g*8 (LSTM xbuf bank spread).
// ---------------------------------------------------------------------------
__global__ __launch_bounds__(256) void gemm_k(
    const unsigned short* __restrict__ embB, const unsigned short* __restrict__ wB,
    const float* __restrict__ bF,  const float* __restrict__ bB,
    unsigned short* __restrict__ xg2,
    const int* __restrict__ pos,
    const float* __restrict__ pWiF, const float* __restrict__ pWhF, const float* __restrict__ pbF,
    const float* __restrict__ pWiB, const float* __restrict__ pWhB, const float* __restrict__ pbB,
    float* __restrict__ po) {
  const int tid = threadIdx.x;
  if (blockIdx.x < 128) {
    // ---------------- pos LSTM (serial, 1 wave active) ----------------
    const int blk = blockIdx.x;
    const int b   = blk & 63;
    const int dir = blk >> 6;
    const float* __restrict__ Wi = dir ? pWiB : pWiF;   // [32][46]
    const float* __restrict__ Wh = dir ? pWhB : pWhF;   // [32][8]
    const float* __restrict__ bias = dir ? pbB : pbF;
    __shared__ float Wis[32 * P1_];
    for (int i = tid; i < 32 * P1_; i += 256) Wis[i] = Wi[i];
    __syncthreads();
    if (tid >= 64) return;
    const int lane = tid;
    float w[8] = {};
    float bi = 0.f;
    if (lane < 32) {
      #pragma unroll
      for (int j = 0; j < 8; ++j) w[j] = Wh[lane * 8 + j];
      bi = bias[lane];
    }
    float h[8] = {};
    float cc = 0.f;
    for (int s = 0; s < T_; ++s) {
      const int tt = dir ? (T_ - 1 - s) : s;
      const int p = pos[b * T_ + tt];
      float acc = 0.f;
      if (lane < 32) {
        acc = Wis[lane * P1_ + p] + bi;
        #pragma unroll
        for (int j = 0; j < 8; ++j) acc += w[j] * h[j];
      }
      const float act = (lane >= 16 && lane < 24) ? ftanh_(acc) : sigmoidf_(acc);
      const float a_f = __shfl_down(act, 8);
      const float a_g = __shfl_down(act, 16);
      const float a_o = __shfl_down(act, 24);
      float hnew = 0.f;
      if (lane < 8) {
        cc = a_f * cc + act * a_g;
        hnew = a_o * ftanh_(cc);
        po[(long)(b * T_ + tt) * 16 + dir * 8 + lane] = hnew;
      }
      #pragma unroll
      for (int j = 0; j < 8; ++j) h[j] = __shfl(hnew, j);
    }
    return;
  }
  // ---------------- xg GEMM (bf16 MFMA, gload_lds staging) ----------------
  __shared__ unsigned short Ast[2][128 * 32];   // 8KB x2, 16B-slot ^ (row&3)
  __shared__ unsigned short Bst[2][64 * 32];    // 4KB x2
  const int xb = blockIdx.x - 128;              // 0..2047
  const int m0 = (xb & 127) * 128;
  const int n0 = (xb >> 7) * 64;
  const int w    = tid >> 6;
  const int lane = tid & 63;
  const int l15  = lane & 15;
  const int lg   = lane >> 4;
  const int mh   = w & 1;
  const int nh   = w >> 1;

  float biasv[2];
  #pragma unroll
  for (int nt = 0; nt < 2; ++nt) {
    const int n = n0 + nh * 32 + nt * 16 + l15;
    biasv[nt] = (n < G4_) ? bF[n] : bB[n - G4_];
  }

  // stage K-chunk kc (32 k): A = embB rows m0..m0+128, B = wB rows n0..n0+64.
  auto stA = [&](int kc, int pb) {
    #pragma unroll
    for (int c = 0; c < 2; ++c) {
      const int uu = c * 256 + tid;              // 16B-unit 0..511
      const int row = uu >> 2, slot = uu & 3;
      const unsigned short* gp =
          embB + (long)(m0 + row) * 320 + kc * 32 + ((slot ^ (row & 3)) << 3);
      gload_lds16(gp, &Ast[pb][(c * 256 + (tid & ~63)) * 8]);
    }
  };
  auto stB = [&](int kc, int pb) {
    const int row = tid >> 2, slot = tid & 3;    // 256 units
    const unsigned short* gp =
        wB + (long)(n0 + row) * 320 + kc * 32 + ((slot ^ (row & 3)) << 3);
    gload_lds16(gp, &Bst[pb][(tid & ~63) * 8]);
  };

  f32x4 acc[4][2];
  #pragma unroll
  for (int mt = 0; mt < 4; ++mt)
    #pragma unroll
    for (int nt = 0; nt < 2; ++nt) acc[mt][nt] = (f32x4){0.f, 0.f, 0.f, 0.f};

  stA(0, 0); stB(0, 0);
  asm volatile("s_waitcnt vmcnt(0)" ::: "memory");
  __syncthreads();
  for (int kc = 0; kc < 10; ++kc) {
    const int cur = kc & 1;
    if (kc < 9) { stA(kc + 1, cur ^ 1); stB(kc + 1, cur ^ 1); }
    short8 bfr[2];
    #pragma unroll
    for (int nt = 0; nt < 2; ++nt) {
      const int r = nh * 32 + nt * 16 + l15;
      bfr[nt] = *(const short8*)&Bst[cur][r * 32 + ((lg ^ (r & 3)) << 3)];
    }
    #pragma unroll
    for (int mt = 0; mt < 4; ++mt) {
      const int r = mh * 64 + mt * 16 + l15;
      const short8 af = *(const short8*)&Ast[cur][r * 32 + ((lg ^ (r & 3)) << 3)];
      #pragma unroll
      for (int nt = 0; nt < 2; ++nt)
        acc[mt][nt] = __builtin_amdgcn_mfma_f32_16x16x32_bf16(af, bfr[nt], acc[mt][nt], 0, 0, 0);
    }
    if (kc < 9) {
      asm volatile("s_waitcnt vmcnt(0)" ::: "memory");
      __syncthreads();
    }
  }
  // epilogue: bias + f2bf + gate-rotated scatter store
  #pragma unroll
  for (int nt = 0; nt < 2; ++nt) {
    const int n = n0 + nh * 32 + nt * 16 + l15;
    const int dir = n >> 9, c = n & 511;
    const int gg = c >> 7, rr = c & 127;
    const int cp = gg * 128 + ((rr + gg * 8) & 127);
    #pragma unroll
    for (int mt = 0; mt < 4; ++mt) {
      #pragma unroll
      for (int r = 0; r < 4; ++r) {
        const int m = m0 + mh * 64 + mt * 16 + lg * 4 + r;
        const int bb_ = m >> 8, tt = m & 255;
        xg2[(long)(((dir * 256 + tt) * 64) + bb_) * 512 + cp] =
            f2bf(acc[mt][nt][r] + biasv[nt]);
      }
    }
  }
}

// ---------------------------------------------------------------------------
// Kernel 2: word LSTM (MFMA + DPP gates), R8/R10 configuration. wo bf16.
// ---------------------------------------------------------------------------
__global__ __launch_bounds__(512) void word_lstm_mfma3(
    const unsigned short* __restrict__ xgb, const float* __restrict__ WhF,
    const float* __restrict__ WhB, unsigned short* __restrict__ wo) {
  const int b    = blockIdx.x >> 1;
  const int dir  = blockIdx.x & 1;
  const int tid  = threadIdx.x;
  const int w    = tid >> 6;
  const int lane = tid & 63;
  const int l15  = lane & 15;
  const int lg   = lane >> 4;
  const int g    = lane & 3;
  const int qloc = l15 >> 2;
  const float* __restrict__ Wh = dir ? WhB : WhF;

  __shared__ unsigned short xbuf[2][16 * 512];            // 32 KB
  __shared__ unsigned short wo_stage[2][16][128];         // 8 KB bf16
  __shared__ __align__(16) unsigned short h2[2][128];

  short8 bfr[4][4];
  #pragma unroll
  for (int nt = 0; nt < 4; ++nt) {
    const int q = w * 16 + nt * 4 + qloc;
    const int r = g * 128 + q;
    #pragma unroll
    for (int kf = 0; kf < 4; ++kf) {
      const float* p = Wh + (long)r * 128 + kf * 32 + lg * 8;
      const float4 f0 = *(const float4*)p;
      const float4 f1 = *(const float4*)(p + 4);
      union { unsigned short u[8]; short8 v; } t;
      t.u[0]=f2bf(f0.x); t.u[1]=f2bf(f0.y); t.u[2]=f2bf(f0.z); t.u[3]=f2bf(f0.w);
      t.u[4]=f2bf(f1.x); t.u[5]=f2bf(f1.y); t.u[6]=f2bf(f1.z); t.u[7]=f2bf(f1.w);
      bfr[nt][kf] = t.v;
    }
  }

  if (tid < 128) { h2[0][tid] = 0; h2[1][tid] = 0; }

  auto stage = [&](int cc, int bb) {
    #pragma unroll
    for (int k = 0; k < 2; ++k) {
      const int j = k * 8 + w;
      const int s_abs = cc * 16 + j;
      const int t = dir ? 255 - s_abs : s_abs;
      const unsigned short* gp =
          xgb + (((long)(dir * 256 + t) * 64 + b) << 9) + lane * 8;
      gload_lds16(gp, &xbuf[bb][j * 512]);
    }
  };

  float cst[4] = {0.f, 0.f, 0.f, 0.f};
  const float kmul = (g == 2) ? 2.f : 1.f;
  const float amul = (g == 2) ? 2.f : 1.f;
  const float aadd = (g == 2) ? -1.f : 0.f;
  int xcol[4];
  #pragma unroll
  for (int nt = 0; nt < 4; ++nt)
    xcol[nt] = g * 128 + ((w * 16 + qloc + nt * 4 + g * 8) & 127);

  stage(0, 0);
  asm volatile("s_waitcnt vmcnt(0)" ::: "memory");
  asm volatile("s_waitcnt lgkmcnt(0)" ::: "memory");
  __builtin_amdgcn_s_barrier();
  stage(1, 1);

  for (int s = 0; s < T_; ++s) {
    const int cc = s >> 4, j = s & 15, cb = cc & 1;
    const unsigned short* hb = h2[s & 1];
    short8 af[4];
    #pragma unroll
    for (int kf = 0; kf < 4; ++kf)
      af[kf] = *(const short8*)(hb + kf * 32 + lg * 8);
    float xqv[4];
    #pragma unroll
    for (int nt = 0; nt < 4; ++nt) {
      const unsigned u = xbuf[cb][j * 512 + xcol[nt]];
      xqv[nt] = __uint_as_float(u << 16);
    }
    f32x4 acc[4];
    #pragma unroll
    for (int nt = 0; nt < 4; ++nt) {
      f32x4 a = {0.f, 0.f, 0.f, 0.f};
      #pragma unroll
      for (int kf = 0; kf < 4; ++kf)
        a = __builtin_amdgcn_mfma_f32_16x16x32_bf16(af[kf], bfr[nt][kf], a, 0, 0, 0);
      acc[nt] = a;
    }
    #pragma unroll
    for (int nt = 0; nt < 4; ++nt) {
      const float x  = acc[nt][0] + xqv[nt];
      const float sg = 1.0f / (1.0f + __expf(-x * kmul));
      const float act = sg * amul + aadd;
      const float vi = qb<0x00>(act);
      const float vf = qb<0x55>(act);
      const float vg = qb<0xAA>(act);
      const float vo = qb<0xFF>(act);
      cst[nt] = vf * cst[nt] + vi * vg;
      const float e2 = __expf(2.0f * cst[nt]);
      const float th = 1.0f - 2.0f / (e2 + 1.0f);
      const float hh = vo * th;
      const unsigned short hb16 = f2bf(hh);
      if (lane < 16 && g == 0) {
        const int q = w * 16 + nt * 4 + qloc;
        h2[(s + 1) & 1][q] = hb16;
        wo_stage[cb][j][q] = hb16;
      }
    }
    if (j == 15 && s < 255) {
      asm volatile("s_waitcnt vmcnt(0)" ::: "memory");
      asm volatile("s_waitcnt lgkmcnt(0)" ::: "memory");
      __builtin_amdgcn_s_barrier();
      {
        const int jf = tid >> 5, qc = (tid & 31) << 2;
        const int s_f = cc * 16 + jf;
        const int tf = dir ? 255 - s_f : s_f;
        const ushort4 v = *(const ushort4*)&wo_stage[cb][jf][qc];
        *(ushort4*)&wo[((long)(b * 256 + tf)) * 256 + dir * 128 + qc] = v;
      }
      if (cc + 2 <= 15) stage(cc + 2, cb);
    } else if (s < 255) {
      asm volatile("s_waitcnt lgkmcnt(0)" ::: "memory");
      __builtin_amdgcn_s_barrier();
    }
  }
  asm volatile("s_waitcnt lgkmcnt(0)" ::: "memory");
  __builtin_amdgcn_s_barrier();
  {
    const int jf = tid >> 5, qc = (tid & 31) << 2;
    const int s_f = 15 * 16 + jf;
    const int tf = dir ? 255 - s_f : s_f;
    const ushort4 v = *(const ushort4*)&wo_stage[1][jf][qc];
    *(ushort4*)&wo[((long)(b * 256 + tf)) * 256 + dir * 128 + qc] = v;
  }
}

// ---------------------------------------------------------------------------
// Kernel 3 (fused): wh+ph+feats.  M-tile 64 -> 256 blocks (full-chip).
// ---------------------------------------------------------------------------
__global__ __launch_bounds__(256) void wh_feats_k(
    const unsigned short* __restrict__ wo,   // [NPOS][256] bf16
    const float* __restrict__ whW, const float* __restrict__ whb,
    const float* __restrict__ po,  const float* __restrict__ phW,
    const float* __restrict__ phb, const float* __restrict__ tagW,
    const float* __restrict__ tagb, float* __restrict__ feats) {
  __shared__ unsigned short Ast[2][64 * 32];     // 4KB x2, 16B-slot ^ (row&3)
  __shared__ unsigned short whs[64 * 128];       // 16KB wh tile bf16, swizzled
  __shared__ float tagWs[6 * 136], tagbs[6], phWs[128], phbs[8], whbs[128];
  const int m0  = blockIdx.x * 64;
  const int tid = threadIdx.x;
  const int w   = tid >> 6;
  const int lane = tid & 63;
  const int l15 = lane & 15, lg = lane >> 4;

  for (int i = tid; i < 816; i += 256) tagWs[i] = tagW[i];
  if (tid < 6)   tagbs[tid] = tagb[tid];
  if (tid < 128) phWs[tid]  = phW[tid];
  if (tid < 8)   phbs[tid]  = phb[tid];
  if (tid < 128) whbs[tid]  = whb[tid];

  short8 bfr[2][8];
  #pragma unroll
  for (int nt = 0; nt < 2; ++nt) {
    const int n = w * 32 + nt * 16 + l15;
    #pragma unroll
    for (int kf = 0; kf < 8; ++kf) {
      const float* p = whW + (long)n * 256 + kf * 32 + lg * 8;
      const float4 f0 = *(const float4*)p;
      const float4 f1 = *(const float4*)(p + 4);
      union { unsigned short u[8]; short8 v; } t;
      t.u[0]=f2bf(f0.x); t.u[1]=f2bf(f0.y); t.u[2]=f2bf(f0.z); t.u[3]=f2bf(f0.w);
      t.u[4]=f2bf(f1.x); t.u[5]=f2bf(f1.y); t.u[6]=f2bf(f1.z); t.u[7]=f2bf(f1.w);
      bfr[nt][kf] = t.v;
    }
  }

  auto stageA = [&](int kc, int pb) {
    const int row  = tid >> 2;                 // 0..63
    const int slot = tid & 3;
    const unsigned short* gp =
        wo + (long)(m0 + row) * 256 + kc * 32 + ((slot ^ (row & 3)) << 3);
    unsigned short* lb = &Ast[pb][(tid & ~63) << 3];
    gload_lds16(gp, lb);
  };

  f32x4 acc[4][2];
  #pragma unroll
  for (int mt = 0; mt < 4; ++mt)
    #pragma unroll
    for (int nt = 0; nt < 2; ++nt) acc[mt][nt] = (f32x4){0.f,0.f,0.f,0.f};

  stageA(0, 0);
  asm volatile("s_waitcnt vmcnt(0)" ::: "memory");
  __syncthreads();
  for (int kc = 0; kc < 8; ++kc) {
    if (kc < 7) stageA(kc + 1, (kc + 1) & 1);
    const unsigned short* ab = &Ast[kc & 1][0];
    #pragma unroll
    for (int mt = 0; mt < 4; ++mt) {
      const int row = mt * 16 + l15;
      const short8 af = *(const short8*)(ab + row * 32 + ((lg ^ (row & 3)) << 3));
      #pragma unroll
      for (int nt = 0; nt < 2; ++nt)
        acc[mt][nt] = __builtin_amdgcn_mfma_f32_16x16x32_bf16(af, bfr[nt][kc], acc[mt][nt], 0, 0, 0);
    }
    if (kc < 7) {
      asm volatile("s_waitcnt vmcnt(0)" ::: "memory");
      __syncthreads();
    }
  }
  #pragma unroll
  for (int nt = 0; nt < 2; ++nt) {
    const int col = w * 32 + nt * 16 + l15;
    const float bv = whbs[col];
    #pragma unroll
    for (int mt = 0; mt < 4; ++mt) {
      #pragma unroll
      for (int r = 0; r < 4; ++r) {
        const int row = mt * 16 + lg * 4 + r;
        const int cs = col ^ ((row & 7) << 3);
        whs[row * 128 + cs] = f2bf(fmaxf(acc[mt][nt][r] + bv, 0.f));
      }
    }
  }
  __syncthreads();
  {
    const int row = tid >> 2, kq = tid & 3;
    float f[6] = {0.f, 0.f, 0.f, 0.f, 0.f, 0.f};
    #pragma unroll
    for (int ks = 0; ks < 4; ++ks) {
      const int k0 = kq * 32 + ks * 8;
      const int slot = (k0 >> 3) ^ (row & 7);
      const short8 v8 = *(const short8*)&whs[row * 128 + slot * 8];
      #pragma unroll
      for (int e = 0; e < 8; ++e) {
        const float wv = bf2f(((unsigned short)v8[e]));
        #pragma unroll
        for (int o = 0; o < 6; ++o) f[o] += wv * tagWs[o * 136 + k0 + e];
      }
    }
    if (kq == 3) {
      const float* pr = po + (long)(m0 + row) * 16;
      float pv[16];
      #pragma unroll
      for (int i = 0; i < 16; i += 4) {
        const float4 v = *(const float4*)(pr + i);
        pv[i] = v.x; pv[i+1] = v.y; pv[i+2] = v.z; pv[i+3] = v.w;
      }
      #pragma unroll
      for (int o8 = 0; o8 < 8; ++o8) {
        float a = phbs[o8];
        #pragma unroll
        for (int k = 0; k < 16; ++k) a += pv[k] * phWs[o8 * 16 + k];
        a = fmaxf(a, 0.f);
        #pragma unroll
        for (int o = 0; o < 6; ++o) f[o] += a * tagWs[o * 136 + 128 + o8];
      }
    }
    #pragma unroll
    for (int o = 0; o < 6; ++o) {
      f[o] += __shfl_xor(f[o], 1);
      f[o] += __shfl_xor(f[o], 2);
    }
    if (kq == 0) {
      #pragma unroll
      for (int o = 0; o < 6; ++o)
        feats[(long)(m0 + row) * 6 + o] = fmaxf(f[o] + tagbs[o], 0.f);
    }
  }
}

// ---------------------------------------------------------------------------
// Kernel 4: CRF NLL. One block, 512 threads; feats prefetched 1 step ahead.
// ---------------------------------------------------------------------------
__global__ __launch_bounds__(512) void crf_k(
    const int* __restrict__ words, const int* __restrict__ labels,
    const float* __restrict__ feats, const float* __restrict__ trans,
    float* __restrict__ out) {
  __shared__ float tn_s[36];
  __shared__ float tE_s[6];
  __shared__ float res_s[64];
  const int tid = threadIdx.x;
  if (tid < 36) {
    const int nx = tid / 6, pv = tid % 6;
    float mx = -1e30f;
    for (int q = 0; q < 6; ++q) mx = fmaxf(mx, trans[q * 6 + pv]);
    float s = 0.f;
    for (int q = 0; q < 6; ++q) s += __expf(trans[q * 6 + pv] - mx);
    tn_s[tid] = (pv == 4) ? -100.f : (__expf(trans[nx * 6 + pv] - mx) / s);
  }
  if (tid < 6) tE_s[tid] = trans[4 * 6 + tid];
  __syncthreads();

  const int lane = tid & 63;
  const int wv   = tid >> 6;
  const int sub  = lane & 7;
  const int b    = wv * 8 + (lane >> 3);

  int cnt = 0;
  for (int t = sub; t < T_; t += 8) cnt += (words[b * T_ + t] != 0) ? 1 : 0;
  cnt += __shfl_xor(cnt, 1); cnt += __shfl_xor(cnt, 2); cnt += __shfl_xor(cnt, 4);
  const int len = cnt;

  float tnr[6];
  #pragma unroll
  for (int p = 0; p < 6; ++p) tnr[p] = (sub < 6) ? tn_s[sub * 6 + p] : -100.f;
  float alpha = (sub == 3) ? 0.f : -100.f;
  float feat_c = (sub < 6) ? feats[(long)(b * T_) * 6 + sub] : 0.f;
  for (int t = 0; t < T_; ++t) {
    float feat_n = 0.f;
    if (t + 1 < T_)
      feat_n = (sub < 6) ? feats[(long)(b * T_ + t + 1) * 6 + sub] : 0.f;
    float ap[6];
    #pragma unroll
    for (int p = 0; p < 6; ++p) ap[p] = __shfl(alpha, p, 8) + tnr[p];
    float m = ap[0];
    #pragma unroll
    for (int p = 1; p < 6; ++p) m = fmaxf(m, ap[p]);
    float s = 0.f;
    #pragma unroll
    for (int p = 0; p < 6; ++p) s += __expf(ap[p] - m);
    const float anew = m + __logf(s) + feat_c;
    alpha = (t < len) ? anew : alpha;
    feat_c = feat_n;
  }
  float v = (sub < 6) ? (alpha + tE_s[sub]) : -1e30f;
  float m2 = v;
  m2 = fmaxf(m2, __shfl_xor(m2, 1));
  m2 = fmaxf(m2, __shfl_xor(m2, 2));
  m2 = fmaxf(m2, __shfl_xor(m2, 4));
  float e = (sub < 6) ? __expf(v - m2) : 0.f;
  e += __shfl_xor(e, 1); e += __shfl_xor(e, 2); e += __shfl_xor(e, 4);
  const float fwd = m2 + __logf(e);

  int fp = T_;
  for (int t = sub; t < T_; t += 8)
    if (labels[b * T_ + t] == 5) fp = min(fp, t);
  fp = min(fp, __shfl_xor(fp, 1));
  fp = min(fp, __shfl_xor(fp, 2));
  fp = min(fp, __shfl_xor(fp, 4));
  float gs = 0.f;
  for (int t = sub; t < T_; t += 8) {
    if (t < fp) {
      const int lab = labels[b * T_ + t];
      const int prv = (t == 0) ? 3 : labels[b * T_ + t - 1];
      gs += feats[(long)(b * T_ + t) * 6 + lab] + tn_s[lab * 6 + prv];
    }
  }
  gs += __shfl_xor(gs, 1); gs += __shfl_xor(gs, 2); gs += __shfl_xor(gs, 4);
  const float gold = gs + trans[4 * 6 + labels[b * T_ + T_ - 1]];
  if (sub == 0) res_s[b] = fwd - gold;
  __syncthreads();
  if (tid == 0) {
    float r = 0.f;
    for (int i = 0; i < 64; ++i) r += res_s[i];
    out[0] = r * (1.0f / 64.0f);
  }
}

// ---------------------------------------------------------------------------
extern "C" void kernel_launch(void* const* d_in, const int* in_sizes, int n_in,
                              void* d_out, int out_size, void* d_ws, size_t ws_size,
                              hipStream_t stream) {
  (void)in_sizes; (void)n_in; (void)out_size; (void)ws_size;
  const int*   words = (const int*)d_in[0];
  const int*   postg = (const int*)d_in[1];
  const int*   labels= (const int*)d_in[2];
  const float* emb_w = (const float*)d_in[3];
  const float* wlfWi = (const float*)d_in[5];
  const float* wlfWh = (const float*)d_in[6];
  const float* wlfb  = (const float*)d_in[7];
  const float* wlbWi = (const float*)d_in[8];
  const float* wlbWh = (const float*)d_in[9];
  const float* wlbb  = (const float*)d_in[10];
  const float* plfWi = (const float*)d_in[11];
  const float* plfWh = (const float*)d_in[12];
  const float* plfb  = (const float*)d_in[13];
  const float* plbWi = (const float*)d_in[14];
  const float* plbWh = (const float*)d_in[15];
  const float* plbb  = (const float*)d_in[16];
  const float* whW   = (const float*)d_in[17];
  const float* whb   = (const float*)d_in[18];
  const float* phW   = (const float*)d_in[19];
  const float* phb   = (const float*)d_in[20];
  const float* tagW  = (const float*)d_in[21];
  const float* tagb  = (const float*)d_in[22];
  const float* trans = (const float*)d_in[23];

  float* ws = (float*)d_ws;
  unsigned short* xg = (unsigned short*)ws;                        // bf16 [2][256][64][512] = NPOS*512 f
  unsigned short* wo = (unsigned short*)(ws + (size_t)NPOS * 512); // bf16 [NPOS][256] = NPOS*128 f
  float* po = ws + (size_t)NPOS * 512 + (size_t)NPOS * 128;        // fp32 [NPOS][16]
  float* fe = po + (size_t)NPOS * 16;                              // fp32 [NPOS][6]
  unsigned short* embB = (unsigned short*)(fe + (size_t)NPOS * 6); // bf16 [16384][320]
  unsigned short* wB   = embB + (size_t)16384 * 320;               // bf16 [1024][320]

  hipLaunchKernelGGL(cast_k, dim3(2720), dim3(256), 0, stream,
                     words, emb_w, wlfWi, wlbWi, embB, wB);
  hipLaunchKernelGGL(gemm_k, dim3(128 + 2048), dim3(256), 0, stream,
                     embB, wB, wlfb, wlbb, xg,
                     postg, plfWi, plfWh, plfb, plbWi, plbWh, plbb, po);
  hipLaunchKernelGGL(word_lstm_mfma3, dim3(128), dim3(512), 0, stream,
                     xg, wlfWh, wlbWh, wo);
  hipLaunchKernelGGL(wh_feats_k, dim3(NPOS / 64), dim3(256), 0, stream,
                     wo, whW, whb, po, phW, phb, tagW, tagb, fe);
  hipLaunchKernelGGL(crf_k, dim3(1), dim3(512), 0, stream,
                     words, labels, fe, trans, (float*)d_out);
}

// Round 12
// 404.981 us; speedup vs baseline: 1.1877x; 1.1877x over previous
//
#include <hip/hip_runtime.h>
#include <hip/hip_bf16.h>
#include <math.h>

#define B_    64
#define T_    256
#define EMB_  300
#define HW_   128
#define G4_   512     // 4*HW
#define P1_   46
#define NPOS  (B_*T_) // 16384

typedef short  short8 __attribute__((ext_vector_type(8)));
typedef float  f32x4  __attribute__((ext_vector_type(4)));

__device__ __forceinline__ float sigmoidf_(float x) {
  return 1.0f / (1.0f + __expf(-x));
}
__device__ __forceinline__ float ftanh_(float x) {
  float e = __expf(2.0f * x);
  return 1.0f - 2.0f / (e + 1.0f);
}
__device__ __forceinline__ unsigned short f2bf(float x) {   // RNE fp32->bf16
  unsigned u = __float_as_uint(x);
  u += 0x7fffu + ((u >> 16) & 1u);
  return (unsigned short)(u >> 16);
}
__device__ __forceinline__ float bf2f(unsigned short u) {
  return __uint_as_float(((unsigned)u) << 16);
}
template<int CTRL>
__device__ __forceinline__ float qb(float v) {   // quad_perm broadcast (DPP, VALU)
  return __int_as_float(__builtin_amdgcn_mov_dpp(__float_as_int(v), CTRL, 0xf, 0xf, true));
}
__device__ __forceinline__ void gload_lds16(const unsigned short* g, unsigned short* l) {
  __builtin_amdgcn_global_load_lds(
      (const __attribute__((address_space(1))) unsigned int*)g,
      (__attribute__((address_space(3))) unsigned int*)l, 16, 0, 0);
}

// ---------------------------------------------------------------------------
// Kernel 0: pre-cast. embB[m][0..320) = bf16(emb[words[m]][k]) (zero-pad
// k>=300); wB[n][0..320) = bf16 of [WiF;WiB] rows. 8 cols per thread.
// ---------------------------------------------------------------------------
__global__ __launch_bounds__(256) void cast_k(
    const int* __restrict__ words, const float* __restrict__ emb,
    const float* __restrict__ WiF, const float* __restrict__ WiB,
    unsigned short* __restrict__ embB, unsigned short* __restrict__ wB) {
  const int u = blockIdx.x * 256 + threadIdx.x;   // < 696320
  const float* src;
  unsigned short* dst;
  int k;
  if (u < 655360) {
    const int m = u / 40, kc = u - m * 40;
    k = kc * 8;
    src = emb + (long)words[m] * EMB_ + k;
    dst = embB + (long)m * 320 + k;
  } else {
    const int u2 = u - 655360;                    // < 40960
    const int n = u2 / 40, kc = u2 - n * 40;
    k = kc * 8;
    src = ((n < G4_) ? WiF + (long)n * EMB_ : WiB + (long)(n - G4_) * EMB_) + k;
    dst = wB + (long)n * 320 + k;
  }
  union { unsigned short us[8]; short8 v; } o;
  if (k + 8 <= EMB_) {
    const float4 a = *(const float4*)src;
    const float4 b = *(const float4*)(src + 4);
    o.us[0]=f2bf(a.x); o.us[1]=f2bf(a.y); o.us[2]=f2bf(a.z); o.us[3]=f2bf(a.w);
    o.us[4]=f2bf(b.x); o.us[5]=f2bf(b.y); o.us[6]=f2bf(b.z); o.us[7]=f2bf(b.w);
  } else if (k < EMB_) {                          // k == 296
    const float4 a = *(const float4*)src;
    o.us[0]=f2bf(a.x); o.us[1]=f2bf(a.y); o.us[2]=f2bf(a.z); o.us[3]=f2bf(a.w);
    o.us[4]=0; o.us[5]=0; o.us[6]=0; o.us[7]=0;
  } else {
    #pragma unroll
    for (int e = 0; e < 8; ++e) o.us[e] = 0;
  }
  *(short8*)dst = o.v;
}

// ---------------------------------------------------------------------------
// Kernel 1: pure xg GEMM (2048 blocks) from pre-cast bf16 tensors via
// global_load_lds. xg (bf16): gate-block g's columns rotated by g*8.
// ---------------------------------------------------------------------------
__global__ __launch_bounds__(256) void gemm_k(
    const unsigned short* __restrict__ embB, const unsigned short* __restrict__ wB,
    const float* __restrict__ bF,  const float* __restrict__ bB,
    unsigned short* __restrict__ xg2) {
  __shared__ unsigned short Ast[2][128 * 32];   // 8KB x2, 16B-slot ^ (row&3)
  __shared__ unsigned short Bst[2][64 * 32];    // 4KB x2
  const int tid = threadIdx.x;
  const int xb = blockIdx.x;                    // 0..2047
  const int m0 = (xb & 127) * 128;
  const int n0 = (xb >> 7) * 64;
  const int w    = tid >> 6;
  const int lane = tid & 63;
  const int l15  = lane & 15;
  const int lg   = lane >> 4;
  const int mh   = w & 1;
  const int nh   = w >> 1;

  float biasv[2];
  #pragma unroll
  for (int nt = 0; nt < 2; ++nt) {
    const int n = n0 + nh * 32 + nt * 16 + l15;
    biasv[nt] = (n < G4_) ? bF[n] : bB[n - G4_];
  }

  auto stA = [&](int kc, int pb) {
    #pragma unroll
    for (int c = 0; c < 2; ++c) {
      const int uu = c * 256 + tid;              // 16B-unit 0..511
      const int row = uu >> 2, slot = uu & 3;
      const unsigned short* gp =
          embB + (long)(m0 + row) * 320 + kc * 32 + ((slot ^ (row & 3)) << 3);
      gload_lds16(gp, &Ast[pb][(c * 256 + (tid & ~63)) * 8]);
    }
  };
  auto stB = [&](int kc, int pb) {
    const int row = tid >> 2, slot = tid & 3;    // 256 units
    const unsigned short* gp =
        wB + (long)(n0 + row) * 320 + kc * 32 + ((slot ^ (row & 3)) << 3);
    gload_lds16(gp, &Bst[pb][(tid & ~63) * 8]);
  };

  f32x4 acc[4][2];
  #pragma unroll
  for (int mt = 0; mt < 4; ++mt)
    #pragma unroll
    for (int nt = 0; nt < 2; ++nt) acc[mt][nt] = (f32x4){0.f, 0.f, 0.f, 0.f};

  stA(0, 0); stB(0, 0);
  asm volatile("s_waitcnt vmcnt(0)" ::: "memory");
  __syncthreads();
  for (int kc = 0; kc < 10; ++kc) {
    const int cur = kc & 1;
    if (kc < 9) { stA(kc + 1, cur ^ 1); stB(kc + 1, cur ^ 1); }
    short8 bfr[2];
    #pragma unroll
    for (int nt = 0; nt < 2; ++nt) {
      const int r = nh * 32 + nt * 16 + l15;
      bfr[nt] = *(const short8*)&Bst[cur][r * 32 + ((lg ^ (r & 3)) << 3)];
    }
    #pragma unroll
    for (int mt = 0; mt < 4; ++mt) {
      const int r = mh * 64 + mt * 16 + l15;
      const short8 af = *(const short8*)&Ast[cur][r * 32 + ((lg ^ (r & 3)) << 3)];
      #pragma unroll
      for (int nt = 0; nt < 2; ++nt)
        acc[mt][nt] = __builtin_amdgcn_mfma_f32_16x16x32_bf16(af, bfr[nt], acc[mt][nt], 0, 0, 0);
    }
    if (kc < 9) {
      asm volatile("s_waitcnt vmcnt(0)" ::: "memory");
      __syncthreads();
    }
  }
  // epilogue: bias + f2bf + gate-rotated scatter store
  #pragma unroll
  for (int nt = 0; nt < 2; ++nt) {
    const int n = n0 + nh * 32 + nt * 16 + l15;
    const int dir = n >> 9, c = n & 511;
    const int gg = c >> 7, rr = c & 127;
    const int cp = gg * 128 + ((rr + gg * 8) & 127);
    #pragma unroll
    for (int mt = 0; mt < 4; ++mt) {
      #pragma unroll
      for (int r = 0; r < 4; ++r) {
        const int m = m0 + mh * 64 + mt * 16 + lg * 4 + r;
        const int bb_ = m >> 8, tt = m & 255;
        xg2[(long)(((dir * 256 + tt) * 64) + bb_) * 512 + cp] =
            f2bf(acc[mt][nt][r] + biasv[nt]);
      }
    }
  }
}

// ---------------------------------------------------------------------------
// Kernel 2 (merged): blocks [0,128) = word LSTM (R8/R10 config, unchanged);
// blocks [128,256) = pos LSTM. The pos chain (~50 us) hides under the word
// LSTM's 283 us on the otherwise-idle half of the chip.
// ---------------------------------------------------------------------------
__global__ __launch_bounds__(512) void lstm_k(
    const unsigned short* __restrict__ xgb, const float* __restrict__ WhF,
    const float* __restrict__ WhB, unsigned short* __restrict__ wo,
    const int* __restrict__ pos,
    const float* __restrict__ pWiF, const float* __restrict__ pWhF, const float* __restrict__ pbF,
    const float* __restrict__ pWiB, const float* __restrict__ pWhB, const float* __restrict__ pbB,
    float* __restrict__ po) {
  const int tid  = threadIdx.x;
  if (blockIdx.x >= 128) {
    // ---------------- pos LSTM ----------------
    const int blk = blockIdx.x - 128;
    const int b   = blk & 63;
    const int dir = blk >> 6;
    const float* __restrict__ Wi = dir ? pWiB : pWiF;   // [32][46]
    const float* __restrict__ Wh = dir ? pWhB : pWhF;   // [32][8]
    const float* __restrict__ bias = dir ? pbB : pbF;
    __shared__ float Wis[32 * P1_];
    for (int i = tid; i < 32 * P1_; i += 512) Wis[i] = Wi[i];
    __syncthreads();
    if (tid >= 64) return;
    const int lane = tid;
    float w[8] = {};
    float bi = 0.f;
    if (lane < 32) {
      #pragma unroll
      for (int j = 0; j < 8; ++j) w[j] = Wh[lane * 8 + j];
      bi = bias[lane];
    }
    float h[8] = {};
    float cc = 0.f;
    for (int s = 0; s < T_; ++s) {
      const int tt = dir ? (T_ - 1 - s) : s;
      const int p = pos[b * T_ + tt];
      float acc = 0.f;
      if (lane < 32) {
        acc = Wis[lane * P1_ + p] + bi;
        #pragma unroll
        for (int j = 0; j < 8; ++j) acc += w[j] * h[j];
      }
      const float act = (lane >= 16 && lane < 24) ? ftanh_(acc) : sigmoidf_(acc);
      const float a_f = __shfl_down(act, 8);
      const float a_g = __shfl_down(act, 16);
      const float a_o = __shfl_down(act, 24);
      float hnew = 0.f;
      if (lane < 8) {
        cc = a_f * cc + act * a_g;
        hnew = a_o * ftanh_(cc);
        po[(long)(b * T_ + tt) * 16 + dir * 8 + lane] = hnew;
      }
      #pragma unroll
      for (int j = 0; j < 8; ++j) h[j] = __shfl(hnew, j);
    }
    return;
  }
  // ---------------- word LSTM (unchanged from R10) ----------------
  const int b    = blockIdx.x >> 1;
  const int dir  = blockIdx.x & 1;
  const int w    = tid >> 6;
  const int lane = tid & 63;
  const int l15  = lane & 15;
  const int lg   = lane >> 4;
  const int g    = lane & 3;
  const int qloc = l15 >> 2;
  const float* __restrict__ Wh = dir ? WhB : WhF;

  __shared__ unsigned short xbuf[2][16 * 512];            // 32 KB
  __shared__ unsigned short wo_stage[2][16][128];         // 8 KB bf16
  __shared__ __align__(16) unsigned short h2[2][128];

  short8 bfr[4][4];
  #pragma unroll
  for (int nt = 0; nt < 4; ++nt) {
    const int q = w * 16 + nt * 4 + qloc;
    const int r = g * 128 + q;
    #pragma unroll
    for (int kf = 0; kf < 4; ++kf) {
      const float* p = Wh + (long)r * 128 + kf * 32 + lg * 8;
      const float4 f0 = *(const float4*)p;
      const float4 f1 = *(const float4*)(p + 4);
      union { unsigned short u[8]; short8 v; } t;
      t.u[0]=f2bf(f0.x); t.u[1]=f2bf(f0.y); t.u[2]=f2bf(f0.z); t.u[3]=f2bf(f0.w);
      t.u[4]=f2bf(f1.x); t.u[5]=f2bf(f1.y); t.u[6]=f2bf(f1.z); t.u[7]=f2bf(f1.w);
      bfr[nt][kf] = t.v;
    }
  }

  if (tid < 128) { h2[0][tid] = 0; h2[1][tid] = 0; }

  auto stage = [&](int cc, int bb) {
    #pragma unroll
    for (int k = 0; k < 2; ++k) {
      const int j = k * 8 + w;
      const int s_abs = cc * 16 + j;
      const int t = dir ? 255 - s_abs : s_abs;
      const unsigned short* gp =
          xgb + (((long)(dir * 256 + t) * 64 + b) << 9) + lane * 8;
      gload_lds16(gp, &xbuf[bb][j * 512]);
    }
  };

  float cst[4] = {0.f, 0.f, 0.f, 0.f};
  const float kmul = (g == 2) ? 2.f : 1.f;
  const float amul = (g == 2) ? 2.f : 1.f;
  const float aadd = (g == 2) ? -1.f : 0.f;
  int xcol[4];
  #pragma unroll
  for (int nt = 0; nt < 4; ++nt)
    xcol[nt] = g * 128 + ((w * 16 + qloc + nt * 4 + g * 8) & 127);

  stage(0, 0);
  asm volatile("s_waitcnt vmcnt(0)" ::: "memory");
  asm volatile("s_waitcnt lgkmcnt(0)" ::: "memory");
  __builtin_amdgcn_s_barrier();
  stage(1, 1);

  for (int s = 0; s < T_; ++s) {
    const int cc = s >> 4, j = s & 15, cb = cc & 1;
    const unsigned short* hb = h2[s & 1];
    short8 af[4];
    #pragma unroll
    for (int kf = 0; kf < 4; ++kf)
      af[kf] = *(const short8*)(hb + kf * 32 + lg * 8);
    float xqv[4];
    #pragma unroll
    for (int nt = 0; nt < 4; ++nt) {
      const unsigned u = xbuf[cb][j * 512 + xcol[nt]];
      xqv[nt] = __uint_as_float(u << 16);
    }
    f32x4 acc[4];
    #pragma unroll
    for (int nt = 0; nt < 4; ++nt) {
      f32x4 a = {0.f, 0.f, 0.f, 0.f};
      #pragma unroll
      for (int kf = 0; kf < 4; ++kf)
        a = __builtin_amdgcn_mfma_f32_16x16x32_bf16(af[kf], bfr[nt][kf], a, 0, 0, 0);
      acc[nt] = a;
    }
    #pragma unroll
    for (int nt = 0; nt < 4; ++nt) {
      const float x  = acc[nt][0] + xqv[nt];
      const float sg = 1.0f / (1.0f + __expf(-x * kmul));
      const float act = sg * amul + aadd;
      const float vi = qb<0x00>(act);
      const float vf = qb<0x55>(act);
      const float vg = qb<0xAA>(act);
      const float vo = qb<0xFF>(act);
      cst[nt] = vf * cst[nt] + vi * vg;
      const float e2 = __expf(2.0f * cst[nt]);
      const float th = 1.0f - 2.0f / (e2 + 1.0f);
      const float hh = vo * th;
      const unsigned short hb16 = f2bf(hh);
      if (lane < 16 && g == 0) {
        const int q = w * 16 + nt * 4 + qloc;
        h2[(s + 1) & 1][q] = hb16;
        wo_stage[cb][j][q] = hb16;
      }
    }
    if (j == 15 && s < 255) {
      asm volatile("s_waitcnt vmcnt(0)" ::: "memory");
      asm volatile("s_waitcnt lgkmcnt(0)" ::: "memory");
      __builtin_amdgcn_s_barrier();
      {
        const int jf = tid >> 5, qc = (tid & 31) << 2;
        const int s_f = cc * 16 + jf;
        const int tf = dir ? 255 - s_f : s_f;
        const ushort4 v = *(const ushort4*)&wo_stage[cb][jf][qc];
        *(ushort4*)&wo[((long)(b * 256 + tf)) * 256 + dir * 128 + qc] = v;
      }
      if (cc + 2 <= 15) stage(cc + 2, cb);
    } else if (s < 255) {
      asm volatile("s_waitcnt lgkmcnt(0)" ::: "memory");
      __builtin_amdgcn_s_barrier();
    }
  }
  asm volatile("s_waitcnt lgkmcnt(0)" ::: "memory");
  __builtin_amdgcn_s_barrier();
  {
    const int jf = tid >> 5, qc = (tid & 31) << 2;
    const int s_f = 15 * 16 + jf;
    const int tf = dir ? 255 - s_f : s_f;
    const ushort4 v = *(const ushort4*)&wo_stage[1][jf][qc];
    *(ushort4*)&wo[((long)(b * 256 + tf)) * 256 + dir * 128 + qc] = v;
  }
}

// ---------------------------------------------------------------------------
// Kernel 3 (fused): wh+ph+feats.  M-tile 64 -> 256 blocks (full-chip).
// ---------------------------------------------------------------------------
__global__ __launch_bounds__(256) void wh_feats_k(
    const unsigned short* __restrict__ wo,   // [NPOS][256] bf16
    const float* __restrict__ whW, const float* __restrict__ whb,
    const float* __restrict__ po,  const float* __restrict__ phW,
    const float* __restrict__ phb, const float* __restrict__ tagW,
    const float* __restrict__ tagb, float* __restrict__ feats) {
  __shared__ unsigned short Ast[2][64 * 32];     // 4KB x2, 16B-slot ^ (row&3)
  __shared__ unsigned short whs[64 * 128];       // 16KB wh tile bf16, swizzled
  __shared__ float tagWs[6 * 136], tagbs[6], phWs[128], phbs[8], whbs[128];
  const int m0  = blockIdx.x * 64;
  const int tid = threadIdx.x;
  const int w   = tid >> 6;
  const int lane = tid & 63;
  const int l15 = lane & 15, lg = lane >> 4;

  for (int i = tid; i < 816; i += 256) tagWs[i] = tagW[i];
  if (tid < 6)   tagbs[tid] = tagb[tid];
  if (tid < 128) phWs[tid]  = phW[tid];
  if (tid < 8)   phbs[tid]  = phb[tid];
  if (tid < 128) whbs[tid]  = whb[tid];

  short8 bfr[2][8];
  #pragma unroll
  for (int nt = 0; nt < 2; ++nt) {
    const int n = w * 32 + nt * 16 + l15;
    #pragma unroll
    for (int kf = 0; kf < 8; ++kf) {
      const float* p = whW + (long)n * 256 + kf * 32 + lg * 8;
      const float4 f0 = *(const float4*)p;
      const float4 f1 = *(const float4*)(p + 4);
      union { unsigned short u[8]; short8 v; } t;
      t.u[0]=f2bf(f0.x); t.u[1]=f2bf(f0.y); t.u[2]=f2bf(f0.z); t.u[3]=f2bf(f0.w);
      t.u[4]=f2bf(f1.x); t.u[5]=f2bf(f1.y); t.u[6]=f2bf(f1.z); t.u[7]=f2bf(f1.w);
      bfr[nt][kf] = t.v;
    }
  }

  auto stageA = [&](int kc, int pb) {
    const int row  = tid >> 2;                 // 0..63
    const int slot = tid & 3;
    const unsigned short* gp =
        wo + (long)(m0 + row) * 256 + kc * 32 + ((slot ^ (row & 3)) << 3);
    unsigned short* lb = &Ast[pb][(tid & ~63) << 3];
    gload_lds16(gp, lb);
  };

  f32x4 acc[4][2];
  #pragma unroll
  for (int mt = 0; mt < 4; ++mt)
    #pragma unroll
    for (int nt = 0; nt < 2; ++nt) acc[mt][nt] = (f32x4){0.f,0.f,0.f,0.f};

  stageA(0, 0);
  asm volatile("s_waitcnt vmcnt(0)" ::: "memory");
  __syncthreads();
  for (int kc = 0; kc < 8; ++kc) {
    if (kc < 7) stageA(kc + 1, (kc + 1) & 1);
    const unsigned short* ab = &Ast[kc & 1][0];
    #pragma unroll
    for (int mt = 0; mt < 4; ++mt) {
      const int row = mt * 16 + l15;
      const short8 af = *(const short8*)(ab + row * 32 + ((lg ^ (row & 3)) << 3));
      #pragma unroll
      for (int nt = 0; nt < 2; ++nt)
        acc[mt][nt] = __builtin_amdgcn_mfma_f32_16x16x32_bf16(af, bfr[nt][kc], acc[mt][nt], 0, 0, 0);
    }
    if (kc < 7) {
      asm volatile("s_waitcnt vmcnt(0)" ::: "memory");
      __syncthreads();
    }
  }
  #pragma unroll
  for (int nt = 0; nt < 2; ++nt) {
    const int col = w * 32 + nt * 16 + l15;
    const float bv = whbs[col];
    #pragma unroll
    for (int mt = 0; mt < 4; ++mt) {
      #pragma unroll
      for (int r = 0; r < 4; ++r) {
        const int row = mt * 16 + lg * 4 + r;
        const int cs = col ^ ((row & 7) << 3);
        whs[row * 128 + cs] = f2bf(fmaxf(acc[mt][nt][r] + bv, 0.f));
      }
    }
  }
  __syncthreads();
  {
    const int row = tid >> 2, kq = tid & 3;
    float f[6] = {0.f, 0.f, 0.f, 0.f, 0.f, 0.f};
    #pragma unroll
    for (int ks = 0; ks < 4; ++ks) {
      const int k0 = kq * 32 + ks * 8;
      const int slot = (k0 >> 3) ^ (row & 7);
      const short8 v8 = *(const short8*)&whs[row * 128 + slot * 8];
      #pragma unroll
      for (int e = 0; e < 8; ++e) {
        const float wv = bf2f(((unsigned short)v8[e]));
        #pragma unroll
        for (int o = 0; o < 6; ++o) f[o] += wv * tagWs[o * 136 + k0 + e];
      }
    }
    if (kq == 3) {
      const float* pr = po + (long)(m0 + row) * 16;
      float pv[16];
      #pragma unroll
      for (int i = 0; i < 16; i += 4) {
        const float4 v = *(const float4*)(pr + i);
        pv[i] = v.x; pv[i+1] = v.y; pv[i+2] = v.z; pv[i+3] = v.w;
      }
      #pragma unroll
      for (int o8 = 0; o8 < 8; ++o8) {
        float a = phbs[o8];
        #pragma unroll
        for (int k = 0; k < 16; ++k) a += pv[k] * phWs[o8 * 16 + k];
        a = fmaxf(a, 0.f);
        #pragma unroll
        for (int o = 0; o < 6; ++o) f[o] += a * tagWs[o * 136 + 128 + o8];
      }
    }
    #pragma unroll
    for (int o = 0; o < 6; ++o) {
      f[o] += __shfl_xor(f[o], 1);
      f[o] += __shfl_xor(f[o], 2);
    }
    if (kq == 0) {
      #pragma unroll
      for (int o = 0; o < 6; ++o)
        feats[(long)(m0 + row) * 6 + o] = fmaxf(f[o] + tagbs[o], 0.f);
    }
  }
}

// ---------------------------------------------------------------------------
// Kernel 4: CRF NLL. One block, 512 threads; feats prefetched 1 step ahead.
// ---------------------------------------------------------------------------
__global__ __launch_bounds__(512) void crf_k(
    const int* __restrict__ words, const int* __restrict__ labels,
    const float* __restrict__ feats, const float* __restrict__ trans,
    float* __restrict__ out) {
  __shared__ float tn_s[36];
  __shared__ float tE_s[6];
  __shared__ float res_s[64];
  const int tid = threadIdx.x;
  if (tid < 36) {
    const int nx = tid / 6, pv = tid % 6;
    float mx = -1e30f;
    for (int q = 0; q < 6; ++q) mx = fmaxf(mx, trans[q * 6 + pv]);
    float s = 0.f;
    for (int q = 0; q < 6; ++q) s += __expf(trans[q * 6 + pv] - mx);
    tn_s[tid] = (pv == 4) ? -100.f : (__expf(trans[nx * 6 + pv] - mx) / s);
  }
  if (tid < 6) tE_s[tid] = trans[4 * 6 + tid];
  __syncthreads();

  const int lane = tid & 63;
  const int wv   = tid >> 6;
  const int sub  = lane & 7;
  const int b    = wv * 8 + (lane >> 3);

  int cnt = 0;
  for (int t = sub; t < T_; t += 8) cnt += (words[b * T_ + t] != 0) ? 1 : 0;
  cnt += __shfl_xor(cnt, 1); cnt += __shfl_xor(cnt, 2); cnt += __shfl_xor(cnt, 4);
  const int len = cnt;

  float tnr[6];
  #pragma unroll
  for (int p = 0; p < 6; ++p) tnr[p] = (sub < 6) ? tn_s[sub * 6 + p] : -100.f;
  float alpha = (sub == 3) ? 0.f : -100.f;
  float feat_c = (sub < 6) ? feats[(long)(b * T_) * 6 + sub] : 0.f;
  for (int t = 0; t < T_; ++t) {
    float feat_n = 0.f;
    if (t + 1 < T_)
      feat_n = (sub < 6) ? feats[(long)(b * T_ + t + 1) * 6 + sub] : 0.f;
    float ap[6];
    #pragma unroll
    for (int p = 0; p < 6; ++p) ap[p] = __shfl(alpha, p, 8) + tnr[p];
    float m = ap[0];
    #pragma unroll
    for (int p = 1; p < 6; ++p) m = fmaxf(m, ap[p]);
    float s = 0.f;
    #pragma unroll
    for (int p = 0; p < 6; ++p) s += __expf(ap[p] - m);
    const float anew = m + __logf(s) + feat_c;
    alpha = (t < len) ? anew : alpha;
    feat_c = feat_n;
  }
  float v = (sub < 6) ? (alpha + tE_s[sub]) : -1e30f;
  float m2 = v;
  m2 = fmaxf(m2, __shfl_xor(m2, 1));
  m2 = fmaxf(m2, __shfl_xor(m2, 2));
  m2 = fmaxf(m2, __shfl_xor(m2, 4));
  float e = (sub < 6) ? __expf(v - m2) : 0.f;
  e += __shfl_xor(e, 1); e += __shfl_xor(e, 2); e += __shfl_xor(e, 4);
  const float fwd = m2 + __logf(e);

  int fp = T_;
  for (int t = sub; t < T_; t += 8)
    if (labels[b * T_ + t] == 5) fp = min(fp, t);
  fp = min(fp, __shfl_xor(fp, 1));
  fp = min(fp, __shfl_xor(fp, 2));
  fp = min(fp, __shfl_xor(fp, 4));
  float gs = 0.f;
  for (int t = sub; t < T_; t += 8) {
    if (t < fp) {
      const int lab = labels[b * T_ + t];
      const int prv = (t == 0) ? 3 : labels[b * T_ + t - 1];
      gs += feats[(long)(b * T_ + t) * 6 + lab] + tn_s[lab * 6 + prv];
    }
  }
  gs += __shfl_xor(gs, 1); gs += __shfl_xor(gs, 2); gs += __shfl_xor(gs, 4);
  const float gold = gs + trans[4 * 6 + labels[b * T_ + T_ - 1]];
  if (sub == 0) res_s[b] = fwd - gold;
  __syncthreads();
  if (tid == 0) {
    float r = 0.f;
    for (int i = 0; i < 64; ++i) r += res_s[i];
    out[0] = r * (1.0f / 64.0f);
  }
}

// ---------------------------------------------------------------------------
extern "C" void kernel_launch(void* const* d_in, const int* in_sizes, int n_in,
                              void* d_out, int out_size, void* d_ws, size_t ws_size,
                              hipStream_t stream) {
  (void)in_sizes; (void)n_in; (void)out_size; (void)ws_size;
  const int*   words = (const int*)d_in[0];
  const int*   postg = (const int*)d_in[1];
  const int*   labels= (const int*)d_in[2];
  const float* emb_w = (const float*)d_in[3];
  const float* wlfWi = (const float*)d_in[5];
  const float* wlfWh = (const float*)d_in[6];
  const float* wlfb  = (const float*)d_in[7];
  const float* wlbWi = (const float*)d_in[8];
  const float* wlbWh = (const float*)d_in[9];
  const float* wlbb  = (const float*)d_in[10];
  const float* plfWi = (const float*)d_in[11];
  const float* plfWh = (const float*)d_in[12];
  const float* plfb  = (const float*)d_in[13];
  const float* plbWi = (const float*)d_in[14];
  const float* plbWh = (const float*)d_in[15];
  const float* plbb  = (const float*)d_in[16];
  const float* whW   = (const float*)d_in[17];
  const float* whb   = (const float*)d_in[18];
  const float* phW   = (const float*)d_in[19];
  const float* phb   = (const float*)d_in[20];
  const float* tagW  = (const float*)d_in[21];
  const float* tagb  = (const float*)d_in[22];
  const float* trans = (const float*)d_in[23];

  float* ws = (float*)d_ws;
  unsigned short* xg = (unsigned short*)ws;                        // bf16 [2][256][64][512] = NPOS*512 f
  unsigned short* wo = (unsigned short*)(ws + (size_t)NPOS * 512); // bf16 [NPOS][256] = NPOS*128 f
  float* po = ws + (size_t)NPOS * 512 + (size_t)NPOS * 128;        // fp32 [NPOS][16]
  float* fe = po + (size_t)NPOS * 16;                              // fp32 [NPOS][6]
  unsigned short* embB = (unsigned short*)(fe + (size_t)NPOS * 6); // bf16 [16384][320]
  unsigned short* wB   = embB + (size_t)16384 * 320;               // bf16 [1024][320]

  hipLaunchKernelGGL(cast_k, dim3(2720), dim3(256), 0, stream,
                     words, emb_w, wlfWi, wlbWi, embB, wB);
  hipLaunchKernelGGL(gemm_k, dim3(2048), dim3(256), 0, stream,
                     embB, wB, wlfb, wlbb, xg);
  hipLaunchKernelGGL(lstm_k, dim3(256), dim3(512), 0, stream,
                     xg, wlfWh, wlbWh, wo,
                     postg, plfWi, plfWh, plfb, plbWi, plbWh, plbb, po);
  hipLaunchKernelGGL(wh_feats_k, dim3(NPOS / 64), dim3(256), 0, stream,
                     wo, whW, whb, po, phW, phb, tagW, tagb, fe);
  hipLaunchKernelGGL(crf_k, dim3(1), dim3(512), 0, stream,
                     words, labels, fe, trans, (float*)d_out);
}

// Round 13
// 381.429 us; speedup vs baseline: 1.2611x; 1.0617x over previous
//
#include <hip/hip_runtime.h>
#include <hip/hip_bf16.h>
#include <math.h>

#define B_    64
#define T_    256
#define EMB_  300
#define HW_   128
#define G4_   512     // 4*HW
#define P1_   46
#define NPOS  (B_*T_) // 16384

typedef short  short8 __attribute__((ext_vector_type(8)));
typedef float  f32x4  __attribute__((ext_vector_type(4)));

__device__ __forceinline__ float sigmoidf_(float x) {
  return 1.0f / (1.0f + __expf(-x));
}
__device__ __forceinline__ float ftanh_(float x) {
  float e = __expf(2.0f * x);
  return 1.0f - 2.0f / (e + 1.0f);
}
__device__ __forceinline__ unsigned short f2bf(float x) {   // RNE fp32->bf16
  unsigned u = __float_as_uint(x);
  u += 0x7fffu + ((u >> 16) & 1u);
  return (unsigned short)(u >> 16);
}
__device__ __forceinline__ float bf2f(unsigned short u) {
  return __uint_as_float(((unsigned)u) << 16);
}
template<int CTRL>
__device__ __forceinline__ float qb(float v) {   // quad_perm broadcast (DPP, VALU)
  return __int_as_float(__builtin_amdgcn_mov_dpp(__float_as_int(v), CTRL, 0xf, 0xf, true));
}
__device__ __forceinline__ void gload_lds16(const unsigned short* g, unsigned short* l) {
  __builtin_amdgcn_global_load_lds(
      (const __attribute__((address_space(1))) unsigned int*)g,
      (__attribute__((address_space(3))) unsigned int*)l, 16, 0, 0);
}

// ---------------------------------------------------------------------------
// Kernel 0: pre-cast. embB[m][0..320) = bf16(emb[words[m]][k]) (zero-pad
// k>=300); wB[n][0..320) = bf16 of [WiF;WiB] rows. 8 cols per thread.
// ---------------------------------------------------------------------------
__global__ __launch_bounds__(256) void cast_k(
    const int* __restrict__ words, const float* __restrict__ emb,
    const float* __restrict__ WiF, const float* __restrict__ WiB,
    unsigned short* __restrict__ embB, unsigned short* __restrict__ wB) {
  const int u = blockIdx.x * 256 + threadIdx.x;   // < 696320
  const float* src;
  unsigned short* dst;
  int k;
  if (u < 655360) {
    const int m = u / 40, kc = u - m * 40;
    k = kc * 8;
    src = emb + (long)words[m] * EMB_ + k;
    dst = embB + (long)m * 320 + k;
  } else {
    const int u2 = u - 655360;                    // < 40960
    const int n = u2 / 40, kc = u2 - n * 40;
    k = kc * 8;
    src = ((n < G4_) ? WiF + (long)n * EMB_ : WiB + (long)(n - G4_) * EMB_) + k;
    dst = wB + (long)n * 320 + k;
  }
  union { unsigned short us[8]; short8 v; } o;
  if (k + 8 <= EMB_) {
    const float4 a = *(const float4*)src;
    const float4 b = *(const float4*)(src + 4);
    o.us[0]=f2bf(a.x); o.us[1]=f2bf(a.y); o.us[2]=f2bf(a.z); o.us[3]=f2bf(a.w);
    o.us[4]=f2bf(b.x); o.us[5]=f2bf(b.y); o.us[6]=f2bf(b.z); o.us[7]=f2bf(b.w);
  } else if (k < EMB_) {                          // k == 296
    const float4 a = *(const float4*)src;
    o.us[0]=f2bf(a.x); o.us[1]=f2bf(a.y); o.us[2]=f2bf(a.z); o.us[3]=f2bf(a.w);
    o.us[4]=0; o.us[5]=0; o.us[6]=0; o.us[7]=0;
  } else {
    #pragma unroll
    for (int e = 0; e < 8; ++e) o.us[e] = 0;
  }
  *(short8*)dst = o.v;
}

// ---------------------------------------------------------------------------
// Kernel 1: pure xg GEMM, K-chunk 64 (5 iterations -> 5 barrier drains).
// LDS rows of 64 ushort = 8 slots of 16B; slot' = slot ^ (row&7) on both
// the staged global source column and the ds_read (involution, m173/G21).
// ---------------------------------------------------------------------------
__global__ __launch_bounds__(256) void gemm_k(
    const unsigned short* __restrict__ embB, const unsigned short* __restrict__ wB,
    const float* __restrict__ bF,  const float* __restrict__ bB,
    unsigned short* __restrict__ xg2) {
  __shared__ unsigned short Ast[2][128 * 64];   // 16KB x2
  __shared__ unsigned short Bst[2][64 * 64];    // 8KB x2
  const int tid = threadIdx.x;
  const int xb = blockIdx.x;                    // 0..2047
  const int m0 = (xb & 127) * 128;
  const int n0 = (xb >> 7) * 64;
  const int w    = tid >> 6;
  const int lane = tid & 63;
  const int l15  = lane & 15;
  const int lg   = lane >> 4;
  const int mh   = w & 1;
  const int nh   = w >> 1;

  float biasv[2];
  #pragma unroll
  for (int nt = 0; nt < 2; ++nt) {
    const int n = n0 + nh * 32 + nt * 16 + l15;
    biasv[nt] = (n < G4_) ? bF[n] : bB[n - G4_];
  }

  // stage K-chunk kc (64 k): A = 128 rows x 8 slots (1024 units), B = 512.
  auto stA = [&](int kc, int pb) {
    #pragma unroll
    for (int c = 0; c < 4; ++c) {
      const int uu = c * 256 + tid;              // 16B-unit 0..1023
      const int row = uu >> 3, slot = uu & 7;
      const unsigned short* gp =
          embB + (long)(m0 + row) * 320 + kc * 64 + ((slot ^ (row & 7)) << 3);
      gload_lds16(gp, &Ast[pb][(c * 256 + (tid & ~63)) * 8]);
    }
  };
  auto stB = [&](int kc, int pb) {
    #pragma unroll
    for (int c = 0; c < 2; ++c) {
      const int uu = c * 256 + tid;              // 16B-unit 0..511
      const int row = uu >> 3, slot = uu & 7;
      const unsigned short* gp =
          wB + (long)(n0 + row) * 320 + kc * 64 + ((slot ^ (row & 7)) << 3);
      gload_lds16(gp, &Bst[pb][(c * 256 + (tid & ~63)) * 8]);
    }
  };

  f32x4 acc[4][2];
  #pragma unroll
  for (int mt = 0; mt < 4; ++mt)
    #pragma unroll
    for (int nt = 0; nt < 2; ++nt) acc[mt][nt] = (f32x4){0.f, 0.f, 0.f, 0.f};

  stA(0, 0); stB(0, 0);
  asm volatile("s_waitcnt vmcnt(0)" ::: "memory");
  __syncthreads();
  for (int kc = 0; kc < 5; ++kc) {
    const int cur = kc & 1;
    if (kc < 4) { stA(kc + 1, cur ^ 1); stB(kc + 1, cur ^ 1); }
    short8 bfr[2][2];
    #pragma unroll
    for (int nt = 0; nt < 2; ++nt) {
      const int r = nh * 32 + nt * 16 + l15;
      #pragma unroll
      for (int kf = 0; kf < 2; ++kf)
        bfr[nt][kf] = *(const short8*)&Bst[cur][r * 64 + (((kf * 4 + lg) ^ (r & 7)) << 3)];
    }
    #pragma unroll
    for (int mt = 0; mt < 4; ++mt) {
      const int r = mh * 64 + mt * 16 + l15;
      #pragma unroll
      for (int kf = 0; kf < 2; ++kf) {
        const short8 af = *(const short8*)&Ast[cur][r * 64 + (((kf * 4 + lg) ^ (r & 7)) << 3)];
        #pragma unroll
        for (int nt = 0; nt < 2; ++nt)
          acc[mt][nt] = __builtin_amdgcn_mfma_f32_16x16x32_bf16(af, bfr[nt][kf], acc[mt][nt], 0, 0, 0);
      }
    }
    if (kc < 4) {
      asm volatile("s_waitcnt vmcnt(0)" ::: "memory");
      __syncthreads();
    }
  }
  // epilogue: bias + f2bf + gate-rotated scatter store
  #pragma unroll
  for (int nt = 0; nt < 2; ++nt) {
    const int n = n0 + nh * 32 + nt * 16 + l15;
    const int dir = n >> 9, c = n & 511;
    const int gg = c >> 7, rr = c & 127;
    const int cp = gg * 128 + ((rr + gg * 8) & 127);
    #pragma unroll
    for (int mt = 0; mt < 4; ++mt) {
      #pragma unroll
      for (int r = 0; r < 4; ++r) {
        const int m = m0 + mh * 64 + mt * 16 + lg * 4 + r;
        const int bb_ = m >> 8, tt = m & 255;
        xg2[(long)(((dir * 256 + tt) * 64) + bb_) * 512 + cp] =
            f2bf(acc[mt][nt][r] + biasv[nt]);
      }
    }
  }
}

// ---------------------------------------------------------------------------
// Kernel 2 (merged): blocks [0,128) = word LSTM (unchanged); [128,256) = pos.
// ---------------------------------------------------------------------------
__global__ __launch_bounds__(512) void lstm_k(
    const unsigned short* __restrict__ xgb, const float* __restrict__ WhF,
    const float* __restrict__ WhB, unsigned short* __restrict__ wo,
    const int* __restrict__ pos,
    const float* __restrict__ pWiF, const float* __restrict__ pWhF, const float* __restrict__ pbF,
    const float* __restrict__ pWiB, const float* __restrict__ pWhB, const float* __restrict__ pbB,
    float* __restrict__ po) {
  const int tid  = threadIdx.x;
  if (blockIdx.x >= 128) {
    // ---------------- pos LSTM ----------------
    const int blk = blockIdx.x - 128;
    const int b   = blk & 63;
    const int dir = blk >> 6;
    const float* __restrict__ Wi = dir ? pWiB : pWiF;   // [32][46]
    const float* __restrict__ Wh = dir ? pWhB : pWhF;   // [32][8]
    const float* __restrict__ bias = dir ? pbB : pbF;
    __shared__ float Wis[32 * P1_];
    for (int i = tid; i < 32 * P1_; i += 512) Wis[i] = Wi[i];
    __syncthreads();
    if (tid >= 64) return;
    const int lane = tid;
    float w[8] = {};
    float bi = 0.f;
    if (lane < 32) {
      #pragma unroll
      for (int j = 0; j < 8; ++j) w[j] = Wh[lane * 8 + j];
      bi = bias[lane];
    }
    float h[8] = {};
    float cc = 0.f;
    for (int s = 0; s < T_; ++s) {
      const int tt = dir ? (T_ - 1 - s) : s;
      const int p = pos[b * T_ + tt];
      float acc = 0.f;
      if (lane < 32) {
        acc = Wis[lane * P1_ + p] + bi;
        #pragma unroll
        for (int j = 0; j < 8; ++j) acc += w[j] * h[j];
      }
      const float act = (lane >= 16 && lane < 24) ? ftanh_(acc) : sigmoidf_(acc);
      const float a_f = __shfl_down(act, 8);
      const float a_g = __shfl_down(act, 16);
      const float a_o = __shfl_down(act, 24);
      float hnew = 0.f;
      if (lane < 8) {
        cc = a_f * cc + act * a_g;
        hnew = a_o * ftanh_(cc);
        po[(long)(b * T_ + tt) * 16 + dir * 8 + lane] = hnew;
      }
      #pragma unroll
      for (int j = 0; j < 8; ++j) h[j] = __shfl(hnew, j);
    }
    return;
  }
  // ---------------- word LSTM (unchanged) ----------------
  const int b    = blockIdx.x >> 1;
  const int dir  = blockIdx.x & 1;
  const int w    = tid >> 6;
  const int lane = tid & 63;
  const int l15  = lane & 15;
  const int lg   = lane >> 4;
  const int g    = lane & 3;
  const int qloc = l15 >> 2;
  const float* __restrict__ Wh = dir ? WhB : WhF;

  __shared__ unsigned short xbuf[2][16 * 512];            // 32 KB
  __shared__ unsigned short wo_stage[2][16][128];         // 8 KB bf16
  __shared__ __align__(16) unsigned short h2[2][128];

  short8 bfr[4][4];
  #pragma unroll
  for (int nt = 0; nt < 4; ++nt) {
    const int q = w * 16 + nt * 4 + qloc;
    const int r = g * 128 + q;
    #pragma unroll
    for (int kf = 0; kf < 4; ++kf) {
      const float* p = Wh + (long)r * 128 + kf * 32 + lg * 8;
      const float4 f0 = *(const float4*)p;
      const float4 f1 = *(const float4*)(p + 4);
      union { unsigned short u[8]; short8 v; } t;
      t.u[0]=f2bf(f0.x); t.u[1]=f2bf(f0.y); t.u[2]=f2bf(f0.z); t.u[3]=f2bf(f0.w);
      t.u[4]=f2bf(f1.x); t.u[5]=f2bf(f1.y); t.u[6]=f2bf(f1.z); t.u[7]=f2bf(f1.w);
      bfr[nt][kf] = t.v;
    }
  }

  if (tid < 128) { h2[0][tid] = 0; h2[1][tid] = 0; }

  auto stage = [&](int cc, int bb) {
    #pragma unroll
    for (int k = 0; k < 2; ++k) {
      const int j = k * 8 + w;
      const int s_abs = cc * 16 + j;
      const int t = dir ? 255 - s_abs : s_abs;
      const unsigned short* gp =
          xgb + (((long)(dir * 256 + t) * 64 + b) << 9) + lane * 8;
      gload_lds16(gp, &xbuf[bb][j * 512]);
    }
  };

  float cst[4] = {0.f, 0.f, 0.f, 0.f};
  const float kmul = (g == 2) ? 2.f : 1.f;
  const float amul = (g == 2) ? 2.f : 1.f;
  const float aadd = (g == 2) ? -1.f : 0.f;
  int xcol[4];
  #pragma unroll
  for (int nt = 0; nt < 4; ++nt)
    xcol[nt] = g * 128 + ((w * 16 + qloc + nt * 4 + g * 8) & 127);

  stage(0, 0);
  asm volatile("s_waitcnt vmcnt(0)" ::: "memory");
  asm volatile("s_waitcnt lgkmcnt(0)" ::: "memory");
  __builtin_amdgcn_s_barrier();
  stage(1, 1);

  for (int s = 0; s < T_; ++s) {
    const int cc = s >> 4, j = s & 15, cb = cc & 1;
    const unsigned short* hb = h2[s & 1];
    short8 af[4];
    #pragma unroll
    for (int kf = 0; kf < 4; ++kf)
      af[kf] = *(const short8*)(hb + kf * 32 + lg * 8);
    float xqv[4];
    #pragma unroll
    for (int nt = 0; nt < 4; ++nt) {
      const unsigned u = xbuf[cb][j * 512 + xcol[nt]];
      xqv[nt] = __uint_as_float(u << 16);
    }
    f32x4 acc[4];
    #pragma unroll
    for (int nt = 0; nt < 4; ++nt) {
      f32x4 a = {0.f, 0.f, 0.f, 0.f};
      #pragma unroll
      for (int kf = 0; kf < 4; ++kf)
        a = __builtin_amdgcn_mfma_f32_16x16x32_bf16(af[kf], bfr[nt][kf], a, 0, 0, 0);
      acc[nt] = a;
    }
    #pragma unroll
    for (int nt = 0; nt < 4; ++nt) {
      const float x  = acc[nt][0] + xqv[nt];
      const float sg = 1.0f / (1.0f + __expf(-x * kmul));
      const float act = sg * amul + aadd;
      const float vi = qb<0x00>(act);
      const float vf = qb<0x55>(act);
      const float vg = qb<0xAA>(act);
      const float vo = qb<0xFF>(act);
      cst[nt] = vf * cst[nt] + vi * vg;
      const float e2 = __expf(2.0f * cst[nt]);
      const float th = 1.0f - 2.0f / (e2 + 1.0f);
      const float hh = vo * th;
      const unsigned short hb16 = f2bf(hh);
      if (lane < 16 && g == 0) {
        const int q = w * 16 + nt * 4 + qloc;
        h2[(s + 1) & 1][q] = hb16;
        wo_stage[cb][j][q] = hb16;
      }
    }
    if (j == 15 && s < 255) {
      asm volatile("s_waitcnt vmcnt(0)" ::: "memory");
      asm volatile("s_waitcnt lgkmcnt(0)" ::: "memory");
      __builtin_amdgcn_s_barrier();
      {
        const int jf = tid >> 5, qc = (tid & 31) << 2;
        const int s_f = cc * 16 + jf;
        const int tf = dir ? 255 - s_f : s_f;
        const ushort4 v = *(const ushort4*)&wo_stage[cb][jf][qc];
        *(ushort4*)&wo[((long)(b * 256 + tf)) * 256 + dir * 128 + qc] = v;
      }
      if (cc + 2 <= 15) stage(cc + 2, cb);
    } else if (s < 255) {
      asm volatile("s_waitcnt lgkmcnt(0)" ::: "memory");
      __builtin_amdgcn_s_barrier();
    }
  }
  asm volatile("s_waitcnt lgkmcnt(0)" ::: "memory");
  __builtin_amdgcn_s_barrier();
  {
    const int jf = tid >> 5, qc = (tid & 31) << 2;
    const int s_f = 15 * 16 + jf;
    const int tf = dir ? 255 - s_f : s_f;
    const ushort4 v = *(const ushort4*)&wo_stage[1][jf][qc];
    *(ushort4*)&wo[((long)(b * 256 + tf)) * 256 + dir * 128 + qc] = v;
  }
}

// ---------------------------------------------------------------------------
// Kernel 3 (fused): wh+ph+feats.  M-tile 64 -> 256 blocks (full-chip).
// ---------------------------------------------------------------------------
__global__ __launch_bounds__(256) void wh_feats_k(
    const unsigned short* __restrict__ wo,   // [NPOS][256] bf16
    const float* __restrict__ whW, const float* __restrict__ whb,
    const float* __restrict__ po,  const float* __restrict__ phW,
    const float* __restrict__ phb, const float* __restrict__ tagW,
    const float* __restrict__ tagb, float* __restrict__ feats) {
  __shared__ unsigned short Ast[2][64 * 32];     // 4KB x2, 16B-slot ^ (row&3)
  __shared__ unsigned short whs[64 * 128];       // 16KB wh tile bf16, swizzled
  __shared__ float tagWs[6 * 136], tagbs[6], phWs[128], phbs[8], whbs[128];
  const int m0  = blockIdx.x * 64;
  const int tid = threadIdx.x;
  const int w   = tid >> 6;
  const int lane = tid & 63;
  const int l15 = lane & 15, lg = lane >> 4;

  for (int i = tid; i < 816; i += 256) tagWs[i] = tagW[i];
  if (tid < 6)   tagbs[tid] = tagb[tid];
  if (tid < 128) phWs[tid]  = phW[tid];
  if (tid < 8)   phbs[tid]  = phb[tid];
  if (tid < 128) whbs[tid]  = whb[tid];

  short8 bfr[2][8];
  #pragma unroll
  for (int nt = 0; nt < 2; ++nt) {
    const int n = w * 32 + nt * 16 + l15;
    #pragma unroll
    for (int kf = 0; kf < 8; ++kf) {
      const float* p = whW + (long)n * 256 + kf * 32 + lg * 8;
      const float4 f0 = *(const float4*)p;
      const float4 f1 = *(const float4*)(p + 4);
      union { unsigned short u[8]; short8 v; } t;
      t.u[0]=f2bf(f0.x); t.u[1]=f2bf(f0.y); t.u[2]=f2bf(f0.z); t.u[3]=f2bf(f0.w);
      t.u[4]=f2bf(f1.x); t.u[5]=f2bf(f1.y); t.u[6]=f2bf(f1.z); t.u[7]=f2bf(f1.w);
      bfr[nt][kf] = t.v;
    }
  }

  auto stageA = [&](int kc, int pb) {
    const int row  = tid >> 2;                 // 0..63
    const int slot = tid & 3;
    const unsigned short* gp =
        wo + (long)(m0 + row) * 256 + kc * 32 + ((slot ^ (row & 3)) << 3);
    unsigned short* lb = &Ast[pb][(tid & ~63) << 3];
    gload_lds16(gp, lb);
  };

  f32x4 acc[4][2];
  #pragma unroll
  for (int mt = 0; mt < 4; ++mt)
    #pragma unroll
    for (int nt = 0; nt < 2; ++nt) acc[mt][nt] = (f32x4){0.f,0.f,0.f,0.f};

  stageA(0, 0);
  asm volatile("s_waitcnt vmcnt(0)" ::: "memory");
  __syncthreads();
  for (int kc = 0; kc < 8; ++kc) {
    if (kc < 7) stageA(kc + 1, (kc + 1) & 1);
    const unsigned short* ab = &Ast[kc & 1][0];
    #pragma unroll
    for (int mt = 0; mt < 4; ++mt) {
      const int row = mt * 16 + l15;
      const short8 af = *(const short8*)(ab + row * 32 + ((lg ^ (row & 3)) << 3));
      #pragma unroll
      for (int nt = 0; nt < 2; ++nt)
        acc[mt][nt] = __builtin_amdgcn_mfma_f32_16x16x32_bf16(af, bfr[nt][kc], acc[mt][nt], 0, 0, 0);
    }
    if (kc < 7) {
      asm volatile("s_waitcnt vmcnt(0)" ::: "memory");
      __syncthreads();
    }
  }
  #pragma unroll
  for (int nt = 0; nt < 2; ++nt) {
    const int col = w * 32 + nt * 16 + l15;
    const float bv = whbs[col];
    #pragma unroll
    for (int mt = 0; mt < 4; ++mt) {
      #pragma unroll
      for (int r = 0; r < 4; ++r) {
        const int row = mt * 16 + lg * 4 + r;
        const int cs = col ^ ((row & 7) << 3);
        whs[row * 128 + cs] = f2bf(fmaxf(acc[mt][nt][r] + bv, 0.f));
      }
    }
  }
  __syncthreads();
  {
    const int row = tid >> 2, kq = tid & 3;
    float f[6] = {0.f, 0.f, 0.f, 0.f, 0.f, 0.f};
    #pragma unroll
    for (int ks = 0; ks < 4; ++ks) {
      const int k0 = kq * 32 + ks * 8;
      const int slot = (k0 >> 3) ^ (row & 7);
      const short8 v8 = *(const short8*)&whs[row * 128 + slot * 8];
      #pragma unroll
      for (int e = 0; e < 8; ++e) {
        const float wv = bf2f(((unsigned short)v8[e]));
        #pragma unroll
        for (int o = 0; o < 6; ++o) f[o] += wv * tagWs[o * 136 + k0 + e];
      }
    }
    if (kq == 3) {
      const float* pr = po + (long)(m0 + row) * 16;
      float pv[16];
      #pragma unroll
      for (int i = 0; i < 16; i += 4) {
        const float4 v = *(const float4*)(pr + i);
        pv[i] = v.x; pv[i+1] = v.y; pv[i+2] = v.z; pv[i+3] = v.w;
      }
      #pragma unroll
      for (int o8 = 0; o8 < 8; ++o8) {
        float a = phbs[o8];
        #pragma unroll
        for (int k = 0; k < 16; ++k) a += pv[k] * phWs[o8 * 16 + k];
        a = fmaxf(a, 0.f);
        #pragma unroll
        for (int o = 0; o < 6; ++o) f[o] += a * tagWs[o * 136 + 128 + o8];
      }
    }
    #pragma unroll
    for (int o = 0; o < 6; ++o) {
      f[o] += __shfl_xor(f[o], 1);
      f[o] += __shfl_xor(f[o], 2);
    }
    if (kq == 0) {
      #pragma unroll
      for (int o = 0; o < 6; ++o)
        feats[(long)(m0 + row) * 6 + o] = fmaxf(f[o] + tagbs[o], 0.f);
    }
  }
}

// ---------------------------------------------------------------------------
// Kernel 4: CRF NLL. 8 blocks x 64 threads (8 batch elems/block, one wave per
// CU); partial sums to ws, reduced by crf_final_k.
// ---------------------------------------------------------------------------
__global__ __launch_bounds__(64) void crf_k(
    const int* __restrict__ words, const int* __restrict__ labels,
    const float* __restrict__ feats, const float* __restrict__ trans,
    float* __restrict__ part) {
  __shared__ float tn_s[36];
  __shared__ float tE_s[6];
  const int tid = threadIdx.x;
  if (tid < 36) {
    const int nx = tid / 6, pv = tid % 6;
    float mx = -1e30f;
    for (int q = 0; q < 6; ++q) mx = fmaxf(mx, trans[q * 6 + pv]);
    float s = 0.f;
    for (int q = 0; q < 6; ++q) s += __expf(trans[q * 6 + pv] - mx);
    tn_s[tid] = (pv == 4) ? -100.f : (__expf(trans[nx * 6 + pv] - mx) / s);
  }
  if (tid < 6) tE_s[tid] = trans[4 * 6 + tid];
  __syncthreads();

  const int sub = tid & 7;
  const int b   = blockIdx.x * 8 + (tid >> 3);

  int cnt = 0;
  for (int t = sub; t < T_; t += 8) cnt += (words[b * T_ + t] != 0) ? 1 : 0;
  cnt += __shfl_xor(cnt, 1); cnt += __shfl_xor(cnt, 2); cnt += __shfl_xor(cnt, 4);
  const int len = cnt;

  float tnr[6];
  #pragma unroll
  for (int p = 0; p < 6; ++p) tnr[p] = (sub < 6) ? tn_s[sub * 6 + p] : -100.f;
  float alpha = (sub == 3) ? 0.f : -100.f;
  float feat_c = (sub < 6) ? feats[(long)(b * T_) * 6 + sub] : 0.f;
  for (int t = 0; t < T_; ++t) {
    float feat_n = 0.f;
    if (t + 1 < T_)
      feat_n = (sub < 6) ? feats[(long)(b * T_ + t + 1) * 6 + sub] : 0.f;
    float ap[6];
    #pragma unroll
    for (int p = 0; p < 6; ++p) ap[p] = __shfl(alpha, p, 8) + tnr[p];
    float m = ap[0];
    #pragma unroll
    for (int p = 1; p < 6; ++p) m = fmaxf(m, ap[p]);
    float s = 0.f;
    #pragma unroll
    for (int p = 0; p < 6; ++p) s += __expf(ap[p] - m);
    const float anew = m + __logf(s) + feat_c;
    alpha = (t < len) ? anew : alpha;
    feat_c = feat_n;
  }
  float v = (sub < 6) ? (alpha + tE_s[sub]) : -1e30f;
  float m2 = v;
  m2 = fmaxf(m2, __shfl_xor(m2, 1));
  m2 = fmaxf(m2, __shfl_xor(m2, 2));
  m2 = fmaxf(m2, __shfl_xor(m2, 4));
  float e = (sub < 6) ? __expf(v - m2) : 0.f;
  e += __shfl_xor(e, 1); e += __shfl_xor(e, 2); e += __shfl_xor(e, 4);
  const float fwd = m2 + __logf(e);

  int fp = T_;
  for (int t = sub; t < T_; t += 8)
    if (labels[b * T_ + t] == 5) fp = min(fp, t);
  fp = min(fp, __shfl_xor(fp, 1));
  fp = min(fp, __shfl_xor(fp, 2));
  fp = min(fp, __shfl_xor(fp, 4));
  float gs = 0.f;
  for (int t = sub; t < T_; t += 8) {
    if (t < fp) {
      const int lab = labels[b * T_ + t];
      const int prv = (t == 0) ? 3 : labels[b * T_ + t - 1];
      gs += feats[(long)(b * T_ + t) * 6 + lab] + tn_s[lab * 6 + prv];
    }
  }
  gs += __shfl_xor(gs, 1); gs += __shfl_xor(gs, 2); gs += __shfl_xor(gs, 4);
  const float gold = gs + trans[4 * 6 + labels[b * T_ + T_ - 1]];
  float r = (sub == 0) ? (fwd - gold) : 0.f;
  r += __shfl_xor(r, 8);
  r += __shfl_xor(r, 16);
  r += __shfl_xor(r, 32);
  if (tid == 0) part[blockIdx.x] = r;
}

__global__ __launch_bounds__(64) void crf_final_k(
    const float* __restrict__ part, float* __restrict__ out) {
  if (threadIdx.x == 0) {
    float s = 0.f;
    #pragma unroll
    for (int i = 0; i < 8; ++i) s += part[i];
    out[0] = s * (1.0f / 64.0f);
  }
}

// ---------------------------------------------------------------------------
extern "C" void kernel_launch(void* const* d_in, const int* in_sizes, int n_in,
                              void* d_out, int out_size, void* d_ws, size_t ws_size,
                              hipStream_t stream) {
  (void)in_sizes; (void)n_in; (void)out_size; (void)ws_size;
  const int*   words = (const int*)d_in[0];
  const int*   postg = (const int*)d_in[1];
  const int*   labels= (const int*)d_in[2];
  const float* emb_w = (const float*)d_in[3];
  const float* wlfWi = (const float*)d_in[5];
  const float* wlfWh = (const float*)d_in[6];
  const float* wlfb  = (const float*)d_in[7];
  const float* wlbWi = (const float*)d_in[8];
  const float* wlbWh = (const float*)d_in[9];
  const float* wlbb  = (const float*)d_in[10];
  const float* plfWi = (const float*)d_in[11];
  const float* plfWh = (const float*)d_in[12];
  const float* plfb  = (const float*)d_in[13];
  const float* plbWi = (const float*)d_in[14];
  const float* plbWh = (const float*)d_in[15];
  const float* plbb  = (const float*)d_in[16];
  const float* whW   = (const float*)d_in[17];
  const float* whb   = (const float*)d_in[18];
  const float* phW   = (const float*)d_in[19];
  const float* phb   = (const float*)d_in[20];
  const float* tagW  = (const float*)d_in[21];
  const float* tagb  = (const float*)d_in[22];
  const float* trans = (const float*)d_in[23];

  float* ws = (float*)d_ws;
  unsigned short* xg = (unsigned short*)ws;                        // bf16 [2][256][64][512]
  unsigned short* wo = (unsigned short*)(ws + (size_t)NPOS * 512); // bf16 [NPOS][256]
  float* po = ws + (size_t)NPOS * 512 + (size_t)NPOS * 128;        // fp32 [NPOS][16]
  float* fe = po + (size_t)NPOS * 16;                              // fp32 [NPOS][6]
  unsigned short* embB = (unsigned short*)(fe + (size_t)NPOS * 6); // bf16 [16384][320]
  unsigned short* wB   = embB + (size_t)16384 * 320;               // bf16 [1024][320]
  float* crf_part = (float*)(wB + (size_t)1024 * 320);             // fp32 [8]

  hipLaunchKernelGGL(cast_k, dim3(2720), dim3(256), 0, stream,
                     words, emb_w, wlfWi, wlbWi, embB, wB);
  hipLaunchKernelGGL(gemm_k, dim3(2048), dim3(256), 0, stream,
                     embB, wB, wlfb, wlbb, xg);
  hipLaunchKernelGGL(lstm_k, dim3(256), dim3(512), 0, stream,
                     xg, wlfWh, wlbWh, wo,
                     postg, plfWi, plfWh, plfb, plbWi, plbWh, plbb, po);
  hipLaunchKernelGGL(wh_feats_k, dim3(NPOS / 64), dim3(256), 0, stream,
                     wo, whW, whb, po, phW, phb, tagW, tagb, fe);
  hipLaunchKernelGGL(crf_k, dim3(8), dim3(64), 0, stream,
                     words, labels, fe, trans, crf_part);
  hipLaunchKernelGGL(crf_final_k, dim3(1), dim3(64), 0, stream,
                     crf_part, (float*)d_out);
}

// Round 14
// 380.781 us; speedup vs baseline: 1.2632x; 1.0017x over previous
//
#include <hip/hip_runtime.h>
#include <hip/hip_bf16.h>
#include <math.h>

#define B_    64
#define T_    256
#define EMB_  300
#define HW_   128
#define G4_   512     // 4*HW
#define P1_   46
#define NPOS  (B_*T_) // 16384

typedef short  short8 __attribute__((ext_vector_type(8)));
typedef float  f32x4  __attribute__((ext_vector_type(4)));

__device__ __forceinline__ float sigmoidf_(float x) {
  return 1.0f / (1.0f + __expf(-x));
}
__device__ __forceinline__ float ftanh_(float x) {
  float e = __expf(2.0f * x);
  return 1.0f - 2.0f / (e + 1.0f);
}
__device__ __forceinline__ unsigned short f2bf(float x) {   // RNE fp32->bf16
  unsigned u = __float_as_uint(x);
  u += 0x7fffu + ((u >> 16) & 1u);
  return (unsigned short)(u >> 16);
}
__device__ __forceinline__ float bf2f(unsigned short u) {
  return __uint_as_float(((unsigned)u) << 16);
}
template<int CTRL>
__device__ __forceinline__ float qb(float v) {   // quad_perm broadcast (DPP, VALU)
  return __int_as_float(__builtin_amdgcn_mov_dpp(__float_as_int(v), CTRL, 0xf, 0xf, true));
}
__device__ __forceinline__ void gload_lds16(const unsigned short* g, unsigned short* l) {
  __builtin_amdgcn_global_load_lds(
      (const __attribute__((address_space(1))) unsigned int*)g,
      (__attribute__((address_space(3))) unsigned int*)l, 16, 0, 0);
}

// ---------------------------------------------------------------------------
// Kernel 0: pre-cast. embB[m][0..320) = bf16(emb[words[m]][k]) (zero-pad
// k>=300); wB[n][0..320) = bf16 of [WiF;WiB] rows. 8 cols per thread.
// ---------------------------------------------------------------------------
__global__ __launch_bounds__(256) void cast_k(
    const int* __restrict__ words, const float* __restrict__ emb,
    const float* __restrict__ WiF, const float* __restrict__ WiB,
    unsigned short* __restrict__ embB, unsigned short* __restrict__ wB) {
  const int u = blockIdx.x * 256 + threadIdx.x;   // < 696320
  const float* src;
  unsigned short* dst;
  int k;
  if (u < 655360) {
    const int m = u / 40, kc = u - m * 40;
    k = kc * 8;
    src = emb + (long)words[m] * EMB_ + k;
    dst = embB + (long)m * 320 + k;
  } else {
    const int u2 = u - 655360;                    // < 40960
    const int n = u2 / 40, kc = u2 - n * 40;
    k = kc * 8;
    src = ((n < G4_) ? WiF + (long)n * EMB_ : WiB + (long)(n - G4_) * EMB_) + k;
    dst = wB + (long)n * 320 + k;
  }
  union { unsigned short us[8]; short8 v; } o;
  if (k + 8 <= EMB_) {
    const float4 a = *(const float4*)src;
    const float4 b = *(const float4*)(src + 4);
    o.us[0]=f2bf(a.x); o.us[1]=f2bf(a.y); o.us[2]=f2bf(a.z); o.us[3]=f2bf(a.w);
    o.us[4]=f2bf(b.x); o.us[5]=f2bf(b.y); o.us[6]=f2bf(b.z); o.us[7]=f2bf(b.w);
  } else if (k < EMB_) {                          // k == 296
    const float4 a = *(const float4*)src;
    o.us[0]=f2bf(a.x); o.us[1]=f2bf(a.y); o.us[2]=f2bf(a.z); o.us[3]=f2bf(a.w);
    o.us[4]=0; o.us[5]=0; o.us[6]=0; o.us[7]=0;
  } else {
    #pragma unroll
    for (int e = 0; e < 8; ++e) o.us[e] = 0;
  }
  *(short8*)dst = o.v;
}

// ---------------------------------------------------------------------------
// Kernel 1: xg GEMM, 128(M)x128(N) tile, K-chunk 64 (5 iters). 1024 blocks.
// slot' = slot ^ (row&7) involution on staged source + ds_read (m173/G21).
// ---------------------------------------------------------------------------
__global__ __launch_bounds__(256) void gemm_k(
    const unsigned short* __restrict__ embB, const unsigned short* __restrict__ wB,
    const float* __restrict__ bF,  const float* __restrict__ bB,
    unsigned short* __restrict__ xg2) {
  __shared__ unsigned short Ast[2][128 * 64];   // 16KB x2
  __shared__ unsigned short Bst[2][128 * 64];   // 16KB x2
  const int tid = threadIdx.x;
  const int xb = blockIdx.x;                    // 0..1023
  const int m0 = (xb & 127) * 128;
  const int n0 = (xb >> 7) * 128;
  const int w    = tid >> 6;
  const int lane = tid & 63;
  const int l15  = lane & 15;
  const int lg   = lane >> 4;
  const int mh   = w & 1;                       // M half (64 rows)
  const int nh   = w >> 1;                      // N half (64 cols)

  float biasv[4];
  #pragma unroll
  for (int nt = 0; nt < 4; ++nt) {
    const int n = n0 + nh * 64 + nt * 16 + l15;
    biasv[nt] = (n < G4_) ? bF[n] : bB[n - G4_];
  }

  // stage K-chunk kc (64 k): A/B = 128 rows x 8 slots = 1024 16B-units each.
  auto stA = [&](int kc, int pb) {
    #pragma unroll
    for (int c = 0; c < 4; ++c) {
      const int uu = c * 256 + tid;
      const int row = uu >> 3, slot = uu & 7;
      const unsigned short* gp =
          embB + (long)(m0 + row) * 320 + kc * 64 + ((slot ^ (row & 7)) << 3);
      gload_lds16(gp, &Ast[pb][(c * 256 + (tid & ~63)) * 8]);
    }
  };
  auto stB = [&](int kc, int pb) {
    #pragma unroll
    for (int c = 0; c < 4; ++c) {
      const int uu = c * 256 + tid;
      const int row = uu >> 3, slot = uu & 7;
      const unsigned short* gp =
          wB + (long)(n0 + row) * 320 + kc * 64 + ((slot ^ (row & 7)) << 3);
      gload_lds16(gp, &Bst[pb][(c * 256 + (tid & ~63)) * 8]);
    }
  };

  f32x4 acc[4][4];
  #pragma unroll
  for (int mt = 0; mt < 4; ++mt)
    #pragma unroll
    for (int nt = 0; nt < 4; ++nt) acc[mt][nt] = (f32x4){0.f, 0.f, 0.f, 0.f};

  stA(0, 0); stB(0, 0);
  asm volatile("s_waitcnt vmcnt(0)" ::: "memory");
  __syncthreads();
  for (int kc = 0; kc < 5; ++kc) {
    const int cur = kc & 1;
    if (kc < 4) { stA(kc + 1, cur ^ 1); stB(kc + 1, cur ^ 1); }
    #pragma unroll
    for (int kf = 0; kf < 2; ++kf) {
      short8 bfr[4];
      #pragma unroll
      for (int nt = 0; nt < 4; ++nt) {
        const int r = nh * 64 + nt * 16 + l15;
        bfr[nt] = *(const short8*)&Bst[cur][r * 64 + (((kf * 4 + lg) ^ (r & 7)) << 3)];
      }
      #pragma unroll
      for (int mt = 0; mt < 4; ++mt) {
        const int r = mh * 64 + mt * 16 + l15;
        const short8 af = *(const short8*)&Ast[cur][r * 64 + (((kf * 4 + lg) ^ (r & 7)) << 3)];
        #pragma unroll
        for (int nt = 0; nt < 4; ++nt)
          acc[mt][nt] = __builtin_amdgcn_mfma_f32_16x16x32_bf16(af, bfr[nt], acc[mt][nt], 0, 0, 0);
      }
    }
    if (kc < 4) {
      asm volatile("s_waitcnt vmcnt(0)" ::: "memory");
      __syncthreads();
    }
  }
  // epilogue: bias + f2bf + gate-rotated scatter store
  #pragma unroll
  for (int nt = 0; nt < 4; ++nt) {
    const int n = n0 + nh * 64 + nt * 16 + l15;
    const int dir = n >> 9, c = n & 511;
    const int gg = c >> 7, rr = c & 127;
    const int cp = gg * 128 + ((rr + gg * 8) & 127);
    #pragma unroll
    for (int mt = 0; mt < 4; ++mt) {
      #pragma unroll
      for (int r = 0; r < 4; ++r) {
        const int m = m0 + mh * 64 + mt * 16 + lg * 4 + r;
        const int bb_ = m >> 8, tt = m & 255;
        xg2[(long)(((dir * 256 + tt) * 64) + bb_) * 512 + cp] =
            f2bf(acc[mt][nt][r] + biasv[nt]);
      }
    }
  }
}

// ---------------------------------------------------------------------------
// Kernel 2 (merged): blocks [0,128) = word LSTM (unchanged); [128,256) = pos.
// ---------------------------------------------------------------------------
__global__ __launch_bounds__(512) void lstm_k(
    const unsigned short* __restrict__ xgb, const float* __restrict__ WhF,
    const float* __restrict__ WhB, unsigned short* __restrict__ wo,
    const int* __restrict__ pos,
    const float* __restrict__ pWiF, const float* __restrict__ pWhF, const float* __restrict__ pbF,
    const float* __restrict__ pWiB, const float* __restrict__ pWhB, const float* __restrict__ pbB,
    float* __restrict__ po) {
  const int tid  = threadIdx.x;
  if (blockIdx.x >= 128) {
    // ---------------- pos LSTM ----------------
    const int blk = blockIdx.x - 128;
    const int b   = blk & 63;
    const int dir = blk >> 6;
    const float* __restrict__ Wi = dir ? pWiB : pWiF;   // [32][46]
    const float* __restrict__ Wh = dir ? pWhB : pWhF;   // [32][8]
    const float* __restrict__ bias = dir ? pbB : pbF;
    __shared__ float Wis[32 * P1_];
    for (int i = tid; i < 32 * P1_; i += 512) Wis[i] = Wi[i];
    __syncthreads();
    if (tid >= 64) return;
    const int lane = tid;
    float w[8] = {};
    float bi = 0.f;
    if (lane < 32) {
      #pragma unroll
      for (int j = 0; j < 8; ++j) w[j] = Wh[lane * 8 + j];
      bi = bias[lane];
    }
    float h[8] = {};
    float cc = 0.f;
    for (int s = 0; s < T_; ++s) {
      const int tt = dir ? (T_ - 1 - s) : s;
      const int p = pos[b * T_ + tt];
      float acc = 0.f;
      if (lane < 32) {
        acc = Wis[lane * P1_ + p] + bi;
        #pragma unroll
        for (int j = 0; j < 8; ++j) acc += w[j] * h[j];
      }
      const float act = (lane >= 16 && lane < 24) ? ftanh_(acc) : sigmoidf_(acc);
      const float a_f = __shfl_down(act, 8);
      const float a_g = __shfl_down(act, 16);
      const float a_o = __shfl_down(act, 24);
      float hnew = 0.f;
      if (lane < 8) {
        cc = a_f * cc + act * a_g;
        hnew = a_o * ftanh_(cc);
        po[(long)(b * T_ + tt) * 16 + dir * 8 + lane] = hnew;
      }
      #pragma unroll
      for (int j = 0; j < 8; ++j) h[j] = __shfl(hnew, j);
    }
    return;
  }
  // ---------------- word LSTM (unchanged) ----------------
  const int b    = blockIdx.x >> 1;
  const int dir  = blockIdx.x & 1;
  const int w    = tid >> 6;
  const int lane = tid & 63;
  const int l15  = lane & 15;
  const int lg   = lane >> 4;
  const int g    = lane & 3;
  const int qloc = l15 >> 2;
  const float* __restrict__ Wh = dir ? WhB : WhF;

  __shared__ unsigned short xbuf[2][16 * 512];            // 32 KB
  __shared__ unsigned short wo_stage[2][16][128];         // 8 KB bf16
  __shared__ __align__(16) unsigned short h2[2][128];

  short8 bfr[4][4];
  #pragma unroll
  for (int nt = 0; nt < 4; ++nt) {
    const int q = w * 16 + nt * 4 + qloc;
    const int r = g * 128 + q;
    #pragma unroll
    for (int kf = 0; kf < 4; ++kf) {
      const float* p = Wh + (long)r * 128 + kf * 32 + lg * 8;
      const float4 f0 = *(const float4*)p;
      const float4 f1 = *(const float4*)(p + 4);
      union { unsigned short u[8]; short8 v; } t;
      t.u[0]=f2bf(f0.x); t.u[1]=f2bf(f0.y); t.u[2]=f2bf(f0.z); t.u[3]=f2bf(f0.w);
      t.u[4]=f2bf(f1.x); t.u[5]=f2bf(f1.y); t.u[6]=f2bf(f1.z); t.u[7]=f2bf(f1.w);
      bfr[nt][kf] = t.v;
    }
  }

  if (tid < 128) { h2[0][tid] = 0; h2[1][tid] = 0; }

  auto stage = [&](int cc, int bb) {
    #pragma unroll
    for (int k = 0; k < 2; ++k) {
      const int j = k * 8 + w;
      const int s_abs = cc * 16 + j;
      const int t = dir ? 255 - s_abs : s_abs;
      const unsigned short* gp =
          xgb + (((long)(dir * 256 + t) * 64 + b) << 9) + lane * 8;
      gload_lds16(gp, &xbuf[bb][j * 512]);
    }
  };

  float cst[4] = {0.f, 0.f, 0.f, 0.f};
  const float kmul = (g == 2) ? 2.f : 1.f;
  const float amul = (g == 2) ? 2.f : 1.f;
  const float aadd = (g == 2) ? -1.f : 0.f;
  int xcol[4];
  #pragma unroll
  for (int nt = 0; nt < 4; ++nt)
    xcol[nt] = g * 128 + ((w * 16 + qloc + nt * 4 + g * 8) & 127);

  stage(0, 0);
  asm volatile("s_waitcnt vmcnt(0)" ::: "memory");
  asm volatile("s_waitcnt lgkmcnt(0)" ::: "memory");
  __builtin_amdgcn_s_barrier();
  stage(1, 1);

  for (int s = 0; s < T_; ++s) {
    const int cc = s >> 4, j = s & 15, cb = cc & 1;
    const unsigned short* hb = h2[s & 1];
    short8 af[4];
    #pragma unroll
    for (int kf = 0; kf < 4; ++kf)
      af[kf] = *(const short8*)(hb + kf * 32 + lg * 8);
    float xqv[4];
    #pragma unroll
    for (int nt = 0; nt < 4; ++nt) {
      const unsigned u = xbuf[cb][j * 512 + xcol[nt]];
      xqv[nt] = __uint_as_float(u << 16);
    }
    f32x4 acc[4];
    #pragma unroll
    for (int nt = 0; nt < 4; ++nt) {
      f32x4 a = {0.f, 0.f, 0.f, 0.f};
      #pragma unroll
      for (int kf = 0; kf < 4; ++kf)
        a = __builtin_amdgcn_mfma_f32_16x16x32_bf16(af[kf], bfr[nt][kf], a, 0, 0, 0);
      acc[nt] = a;
    }
    #pragma unroll
    for (int nt = 0; nt < 4; ++nt) {
      const float x  = acc[nt][0] + xqv[nt];
      const float sg = 1.0f / (1.0f + __expf(-x * kmul));
      const float act = sg * amul + aadd;
      const float vi = qb<0x00>(act);
      const float vf = qb<0x55>(act);
      const float vg = qb<0xAA>(act);
      const float vo = qb<0xFF>(act);
      cst[nt] = vf * cst[nt] + vi * vg;
      const float e2 = __expf(2.0f * cst[nt]);
      const float th = 1.0f - 2.0f / (e2 + 1.0f);
      const float hh = vo * th;
      const unsigned short hb16 = f2bf(hh);
      if (lane < 16 && g == 0) {
        const int q = w * 16 + nt * 4 + qloc;
        h2[(s + 1) & 1][q] = hb16;
        wo_stage[cb][j][q] = hb16;
      }
    }
    if (j == 15 && s < 255) {
      asm volatile("s_waitcnt vmcnt(0)" ::: "memory");
      asm volatile("s_waitcnt lgkmcnt(0)" ::: "memory");
      __builtin_amdgcn_s_barrier();
      {
        const int jf = tid >> 5, qc = (tid & 31) << 2;
        const int s_f = cc * 16 + jf;
        const int tf = dir ? 255 - s_f : s_f;
        const ushort4 v = *(const ushort4*)&wo_stage[cb][jf][qc];
        *(ushort4*)&wo[((long)(b * 256 + tf)) * 256 + dir * 128 + qc] = v;
      }
      if (cc + 2 <= 15) stage(cc + 2, cb);
    } else if (s < 255) {
      asm volatile("s_waitcnt lgkmcnt(0)" ::: "memory");
      __builtin_amdgcn_s_barrier();
    }
  }
  asm volatile("s_waitcnt lgkmcnt(0)" ::: "memory");
  __builtin_amdgcn_s_barrier();
  {
    const int jf = tid >> 5, qc = (tid & 31) << 2;
    const int s_f = 15 * 16 + jf;
    const int tf = dir ? 255 - s_f : s_f;
    const ushort4 v = *(const ushort4*)&wo_stage[1][jf][qc];
    *(ushort4*)&wo[((long)(b * 256 + tf)) * 256 + dir * 128 + qc] = v;
  }
}

// ---------------------------------------------------------------------------
// Kernel 3 (fused): wh+ph+feats. M-tile 64, K-chunk 64 (4 iters). 256 blocks.
// ---------------------------------------------------------------------------
__global__ __launch_bounds__(256) void wh_feats_k(
    const unsigned short* __restrict__ wo,   // [NPOS][256] bf16
    const float* __restrict__ whW, const float* __restrict__ whb,
    const float* __restrict__ po,  const float* __restrict__ phW,
    const float* __restrict__ phb, const float* __restrict__ tagW,
    const float* __restrict__ tagb, float* __restrict__ feats) {
  __shared__ unsigned short Ast[2][64 * 64];     // 8KB x2, slot ^ (row&7)
  __shared__ unsigned short whs[64 * 128];       // 16KB wh tile bf16, swizzled
  __shared__ float tagWs[6 * 136], tagbs[6], phWs[128], phbs[8], whbs[128];
  const int m0  = blockIdx.x * 64;
  const int tid = threadIdx.x;
  const int w   = tid >> 6;
  const int lane = tid & 63;
  const int l15 = lane & 15, lg = lane >> 4;

  for (int i = tid; i < 816; i += 256) tagWs[i] = tagW[i];
  if (tid < 6)   tagbs[tid] = tagb[tid];
  if (tid < 128) phWs[tid]  = phW[tid];
  if (tid < 8)   phbs[tid]  = phb[tid];
  if (tid < 128) whbs[tid]  = whb[tid];

  short8 bfr[2][8];
  #pragma unroll
  for (int nt = 0; nt < 2; ++nt) {
    const int n = w * 32 + nt * 16 + l15;
    #pragma unroll
    for (int kf = 0; kf < 8; ++kf) {
      const float* p = whW + (long)n * 256 + kf * 32 + lg * 8;
      const float4 f0 = *(const float4*)p;
      const float4 f1 = *(const float4*)(p + 4);
      union { unsigned short u[8]; short8 v; } t;
      t.u[0]=f2bf(f0.x); t.u[1]=f2bf(f0.y); t.u[2]=f2bf(f0.z); t.u[3]=f2bf(f0.w);
      t.u[4]=f2bf(f1.x); t.u[5]=f2bf(f1.y); t.u[6]=f2bf(f1.z); t.u[7]=f2bf(f1.w);
      bfr[nt][kf] = t.v;
    }
  }

  // stage K-chunk kc (64 k): 64 rows x 8 slots = 512 16B-units.
  auto stageA = [&](int kc, int pb) {
    #pragma unroll
    for (int c = 0; c < 2; ++c) {
      const int uu = c * 256 + tid;
      const int row = uu >> 3, slot = uu & 7;
      const unsigned short* gp =
          wo + (long)(m0 + row) * 256 + kc * 64 + ((slot ^ (row & 7)) << 3);
      gload_lds16(gp, &Ast[pb][(c * 256 + (tid & ~63)) * 8]);
    }
  };

  f32x4 acc[4][2];
  #pragma unroll
  for (int mt = 0; mt < 4; ++mt)
    #pragma unroll
    for (int nt = 0; nt < 2; ++nt) acc[mt][nt] = (f32x4){0.f,0.f,0.f,0.f};

  stageA(0, 0);
  asm volatile("s_waitcnt vmcnt(0)" ::: "memory");
  __syncthreads();
  for (int kc = 0; kc < 4; ++kc) {
    if (kc < 3) stageA(kc + 1, (kc + 1) & 1);
    const unsigned short* ab = &Ast[kc & 1][0];
    #pragma unroll
    for (int kf2 = 0; kf2 < 2; ++kf2) {
      #pragma unroll
      for (int mt = 0; mt < 4; ++mt) {
        const int row = mt * 16 + l15;
        const short8 af =
            *(const short8*)(ab + row * 64 + (((kf2 * 4 + lg) ^ (row & 7)) << 3));
        #pragma unroll
        for (int nt = 0; nt < 2; ++nt)
          acc[mt][nt] = __builtin_amdgcn_mfma_f32_16x16x32_bf16(
              af, bfr[nt][kc * 2 + kf2], acc[mt][nt], 0, 0, 0);
      }
    }
    if (kc < 3) {
      asm volatile("s_waitcnt vmcnt(0)" ::: "memory");
      __syncthreads();
    }
  }
  #pragma unroll
  for (int nt = 0; nt < 2; ++nt) {
    const int col = w * 32 + nt * 16 + l15;
    const float bv = whbs[col];
    #pragma unroll
    for (int mt = 0; mt < 4; ++mt) {
      #pragma unroll
      for (int r = 0; r < 4; ++r) {
        const int row = mt * 16 + lg * 4 + r;
        const int cs = col ^ ((row & 7) << 3);
        whs[row * 128 + cs] = f2bf(fmaxf(acc[mt][nt][r] + bv, 0.f));
      }
    }
  }
  __syncthreads();
  {
    const int row = tid >> 2, kq = tid & 3;
    float f[6] = {0.f, 0.f, 0.f, 0.f, 0.f, 0.f};
    #pragma unroll
    for (int ks = 0; ks < 4; ++ks) {
      const int k0 = kq * 32 + ks * 8;
      const int slot = (k0 >> 3) ^ (row & 7);
      const short8 v8 = *(const short8*)&whs[row * 128 + slot * 8];
      #pragma unroll
      for (int e = 0; e < 8; ++e) {
        const float wv = bf2f(((unsigned short)v8[e]));
        #pragma unroll
        for (int o = 0; o < 6; ++o) f[o] += wv * tagWs[o * 136 + k0 + e];
      }
    }
    if (kq == 3) {
      const float* pr = po + (long)(m0 + row) * 16;
      float pv[16];
      #pragma unroll
      for (int i = 0; i < 16; i += 4) {
        const float4 v = *(const float4*)(pr + i);
        pv[i] = v.x; pv[i+1] = v.y; pv[i+2] = v.z; pv[i+3] = v.w;
      }
      #pragma unroll
      for (int o8 = 0; o8 < 8; ++o8) {
        float a = phbs[o8];
        #pragma unroll
        for (int k = 0; k < 16; ++k) a += pv[k] * phWs[o8 * 16 + k];
        a = fmaxf(a, 0.f);
        #pragma unroll
        for (int o = 0; o < 6; ++o) f[o] += a * tagWs[o * 136 + 128 + o8];
      }
    }
    #pragma unroll
    for (int o = 0; o < 6; ++o) {
      f[o] += __shfl_xor(f[o], 1);
      f[o] += __shfl_xor(f[o], 2);
    }
    if (kq == 0) {
      #pragma unroll
      for (int o = 0; o < 6; ++o)
        feats[(long)(m0 + row) * 6 + o] = fmaxf(f[o] + tagbs[o], 0.f);
    }
  }
}

// ---------------------------------------------------------------------------
// Kernel 4: CRF NLL. 8 blocks x 64 threads; partials reduced by crf_final_k.
// ---------------------------------------------------------------------------
__global__ __launch_bounds__(64) void crf_k(
    const int* __restrict__ words, const int* __restrict__ labels,
    const float* __restrict__ feats, const float* __restrict__ trans,
    float* __restrict__ part) {
  __shared__ float tn_s[36];
  __shared__ float tE_s[6];
  const int tid = threadIdx.x;
  if (tid < 36) {
    const int nx = tid / 6, pv = tid % 6;
    float mx = -1e30f;
    for (int q = 0; q < 6; ++q) mx = fmaxf(mx, trans[q * 6 + pv]);
    float s = 0.f;
    for (int q = 0; q < 6; ++q) s += __expf(trans[q * 6 + pv] - mx);
    tn_s[tid] = (pv == 4) ? -100.f : (__expf(trans[nx * 6 + pv] - mx) / s);
  }
  if (tid < 6) tE_s[tid] = trans[4 * 6 + tid];
  __syncthreads();

  const int sub = tid & 7;
  const int b   = blockIdx.x * 8 + (tid >> 3);

  int cnt = 0;
  for (int t = sub; t < T_; t += 8) cnt += (words[b * T_ + t] != 0) ? 1 : 0;
  cnt += __shfl_xor(cnt, 1); cnt += __shfl_xor(cnt, 2); cnt += __shfl_xor(cnt, 4);
  const int len = cnt;

  float tnr[6];
  #pragma unroll
  for (int p = 0; p < 6; ++p) tnr[p] = (sub < 6) ? tn_s[sub * 6 + p] : -100.f;
  float alpha = (sub == 3) ? 0.f : -100.f;
  float feat_c = (sub < 6) ? feats[(long)(b * T_) * 6 + sub] : 0.f;
  for (int t = 0; t < T_; ++t) {
    float feat_n = 0.f;
    if (t + 1 < T_)
      feat_n = (sub < 6) ? feats[(long)(b * T_ + t + 1) * 6 + sub] : 0.f;
    float ap[6];
    #pragma unroll
    for (int p = 0; p < 6; ++p) ap[p] = __shfl(alpha, p, 8) + tnr[p];
    float m = ap[0];
    #pragma unroll
    for (int p = 1; p < 6; ++p) m = fmaxf(m, ap[p]);
    float s = 0.f;
    #pragma unroll
    for (int p = 0; p < 6; ++p) s += __expf(ap[p] - m);
    const float anew = m + __logf(s) + feat_c;
    alpha = (t < len) ? anew : alpha;
    feat_c = feat_n;
  }
  float v = (sub < 6) ? (alpha + tE_s[sub]) : -1e30f;
  float m2 = v;
  m2 = fmaxf(m2, __shfl_xor(m2, 1));
  m2 = fmaxf(m2, __shfl_xor(m2, 2));
  m2 = fmaxf(m2, __shfl_xor(m2, 4));
  float e = (sub < 6) ? __expf(v - m2) : 0.f;
  e += __shfl_xor(e, 1); e += __shfl_xor(e, 2); e += __shfl_xor(e, 4);
  const float fwd = m2 + __logf(e);

  int fp = T_;
  for (int t = sub; t < T_; t += 8)
    if (labels[b * T_ + t] == 5) fp = min(fp, t);
  fp = min(fp, __shfl_xor(fp, 1));
  fp = min(fp, __shfl_xor(fp, 2));
  fp = min(fp, __shfl_xor(fp, 4));
  float gs = 0.f;
  for (int t = sub; t < T_; t += 8) {
    if (t < fp) {
      const int lab = labels[b * T_ + t];
      const int prv = (t == 0) ? 3 : labels[b * T_ + t - 1];
      gs += feats[(long)(b * T_ + t) * 6 + lab] + tn_s[lab * 6 + prv];
    }
  }
  gs += __shfl_xor(gs, 1); gs += __shfl_xor(gs, 2); gs += __shfl_xor(gs, 4);
  const float gold = gs + trans[4 * 6 + labels[b * T_ + T_ - 1]];
  float r = (sub == 0) ? (fwd - gold) : 0.f;
  r += __shfl_xor(r, 8);
  r += __shfl_xor(r, 16);
  r += __shfl_xor(r, 32);
  if (tid == 0) part[blockIdx.x] = r;
}

__global__ __launch_bounds__(64) void crf_final_k(
    const float* __restrict__ part, float* __restrict__ out) {
  if (threadIdx.x == 0) {
    float s = 0.f;
    #pragma unroll
    for (int i = 0; i < 8; ++i) s += part[i];
    out[0] = s * (1.0f / 64.0f);
  }
}

// ---------------------------------------------------------------------------
extern "C" void kernel_launch(void* const* d_in, const int* in_sizes, int n_in,
                              void* d_out, int out_size, void* d_ws, size_t ws_size,
                              hipStream_t stream) {
  (void)in_sizes; (void)n_in; (void)out_size; (void)ws_size;
  const int*   words = (const int*)d_in[0];
  const int*   postg = (const int*)d_in[1];
  const int*   labels= (const int*)d_in[2];
  const float* emb_w = (const float*)d_in[3];
  const float* wlfWi = (const float*)d_in[5];
  const float* wlfWh = (const float*)d_in[6];
  const float* wlfb  = (const float*)d_in[7];
  const float* wlbWi = (const float*)d_in[8];
  const float* wlbWh = (const float*)d_in[9];
  const float* wlbb  = (const float*)d_in[10];
  const float* plfWi = (const float*)d_in[11];
  const float* plfWh = (const float*)d_in[12];
  const float* plfb  = (const float*)d_in[13];
  const float* plbWi = (const float*)d_in[14];
  const float* plbWh = (const float*)d_in[15];
  const float* plbb  = (const float*)d_in[16];
  const float* whW   = (const float*)d_in[17];
  const float* whb   = (const float*)d_in[18];
  const float* phW   = (const float*)d_in[19];
  const float* phb   = (const float*)d_in[20];
  const float* tagW  = (const float*)d_in[21];
  const float* tagb  = (const float*)d_in[22];
  const float* trans = (const float*)d_in[23];

  float* ws = (float*)d_ws;
  unsigned short* xg = (unsigned short*)ws;                        // bf16 [2][256][64][512]
  unsigned short* wo = (unsigned short*)(ws + (size_t)NPOS * 512); // bf16 [NPOS][256]
  float* po = ws + (size_t)NPOS * 512 + (size_t)NPOS * 128;        // fp32 [NPOS][16]
  float* fe = po + (size_t)NPOS * 16;                              // fp32 [NPOS][6]
  unsigned short* embB = (unsigned short*)(fe + (size_t)NPOS * 6); // bf16 [16384][320]
  unsigned short* wB   = embB + (size_t)16384 * 320;               // bf16 [1024][320]
  float* crf_part = (float*)(wB + (size_t)1024 * 320);             // fp32 [8]

  hipLaunchKernelGGL(cast_k, dim3(2720), dim3(256), 0, stream,
                     words, emb_w, wlfWi, wlbWi, embB, wB);
  hipLaunchKernelGGL(gemm_k, dim3(1024), dim3(256), 0, stream,
                     embB, wB, wlfb, wlbb, xg);
  hipLaunchKernelGGL(lstm_k, dim3(256), dim3(512), 0, stream,
                     xg, wlfWh, wlbWh, wo,
                     postg, plfWi, plfWh, plfb, plbWi, plbWh, plbb, po);
  hipLaunchKernelGGL(wh_feats_k, dim3(NPOS / 64), dim3(256), 0, stream,
                     wo, whW, whb, po, phW, phb, tagW, tagb, fe);
  hipLaunchKernelGGL(crf_k, dim3(8), dim3(64), 0, stream,
                     words, labels, fe, trans, crf_part);
  hipLaunchKernelGGL(crf_final_k, dim3(1), dim3(64), 0, stream,
                     crf_part, (float*)d_out);
}